// Round 1
// baseline (20648.778 us; speedup 1.0000x reference)
//
#include <hip/hip_runtime.h>
#include <cstdint>
#include <cstddef>

// Problem constants (validated against in_sizes at runtime where possible)
#define XF 10
#define NF 100
#define HF 200

static __device__ __forceinline__ float bn_scale(float g) {
    return g * 0.9999950000374997f; // 1/sqrt(1 + 1e-5)
}

// ---------------- CSR build ----------------
__global__ __launch_bounds__(256) void hist_kernel(const int* __restrict__ eidx,
                                                   int* __restrict__ counts, int E) {
    int e = blockIdx.x * 256 + threadIdx.x;
    if (e < E) atomicAdd(&counts[eidx[E + e]], 1);
}

__global__ __launch_bounds__(256) void scan1_kernel(const int* __restrict__ counts,
                                                    int* __restrict__ incl,
                                                    int* __restrict__ blocksum, int n) {
    __shared__ int s[256];
    int t = threadIdx.x;
    int base = blockIdx.x * 1024 + t * 4;
    int v0 = (base + 0 < n) ? counts[base + 0] : 0;
    int v1 = (base + 1 < n) ? counts[base + 1] : 0;
    int v2 = (base + 2 < n) ? counts[base + 2] : 0;
    int v3 = (base + 3 < n) ? counts[base + 3] : 0;
    int tot = v0 + v1 + v2 + v3;
    s[t] = tot;
    __syncthreads();
    for (int off = 1; off < 256; off <<= 1) {
        int add = (t >= off) ? s[t - off] : 0;
        __syncthreads();
        s[t] += add;
        __syncthreads();
    }
    int run = s[t] - tot; // exclusive prefix within block
    run += v0; if (base + 0 < n) incl[base + 0] = run;
    run += v1; if (base + 1 < n) incl[base + 1] = run;
    run += v2; if (base + 2 < n) incl[base + 2] = run;
    run += v3; if (base + 3 < n) incl[base + 3] = run;
    if (t == 255) blocksum[blockIdx.x] = s[255];
}

__global__ void scan2_kernel(int* __restrict__ blocksum, int nb) {
    if (blockIdx.x == 0 && threadIdx.x == 0) {
        int r = 0;
        for (int i = 0; i < nb; ++i) { int t = blocksum[i]; blocksum[i] = r; r += t; }
    }
}

__global__ __launch_bounds__(256) void scan3_kernel(const int* __restrict__ incl,
                                                    const int* __restrict__ blockoff,
                                                    int* __restrict__ indptr,
                                                    int* __restrict__ fillpos, int n) {
    int i = blockIdx.x * 256 + threadIdx.x;
    if (i >= n) return;
    int v = incl[i] + blockoff[i >> 10];
    indptr[i + 1] = v;
    fillpos[i + 1] = v;
    if (i == 0) { indptr[0] = 0; fillpos[0] = 0; }
}

__global__ __launch_bounds__(256) void fill_kernel(const int* __restrict__ eidx,
                                                   int* __restrict__ fillpos,
                                                   int* __restrict__ esrc, int E) {
    int e = blockIdx.x * 256 + threadIdx.x;
    if (e >= E) return;
    int d = eidx[E + e];
    int p = atomicAdd(&fillpos[d], 1);
    esrc[p] = eidx[e];
}

__global__ __launch_bounds__(256) void cnt_kernel(const int* __restrict__ batch,
                                                  int* __restrict__ cnt, int n) {
    int i = blockIdx.x * 256 + threadIdx.x;
    if (i < n) atomicAdd(&cnt[batch[i]], 1);
}

// ---------------- layer-1 input linear (10 -> 100, both src & dst transforms) --------
__global__ __launch_bounds__(256) void lin10_kernel(const float* __restrict__ x,
                                                    const float* __restrict__ sw,
                                                    const float* __restrict__ sb,
                                                    const float* __restrict__ dw,
                                                    const float* __restrict__ db,
                                                    float* __restrict__ hsrc,
                                                    float* __restrict__ xd, int n_nodes) {
    int idx = blockIdx.x * 256 + threadIdx.x;
    if (idx >= n_nodes * NF) return;
    int n = idx / NF, f = idx % NF;
    float xv[XF];
#pragma unroll
    for (int k = 0; k < XF; ++k) xv[k] = x[n * XF + k];
    float a = sb[f], b = db[f];
#pragma unroll
    for (int k = 0; k < XF; ++k) {
        a += xv[k] * sw[f * XF + k];
        b += xv[k] * dw[f * XF + k];
    }
    hsrc[idx] = a;
    xd[idx] = b;
}

// ---------------- softmax aggregation (GENConv) ----------------
// one block per node, lane f handles feature f; two passes over edge list
__global__ __launch_bounds__(128) void agg_kernel(const float* __restrict__ h,
                                                  const float* __restrict__ xd,
                                                  const int* __restrict__ indptr,
                                                  const int* __restrict__ esrc,
                                                  float* __restrict__ out) {
    int n = blockIdx.x;
    int f = threadIdx.x;
    if (f >= NF) return;
    int beg = indptr[n], end = indptr[n + 1];
    float maxv = 0.f;
    for (int j = beg; j < end; ++j) {
        int s = esrc[j];
        float v = fmaxf(h[(size_t)s * NF + f], 0.f) + 1e-7f;
        maxv = fmaxf(maxv, v);
    }
    float den = 0.f, num = 0.f;
    for (int j = beg; j < end; ++j) {
        int s = esrc[j];
        float v = fmaxf(h[(size_t)s * NF + f], 0.f) + 1e-7f;
        float e = __expf(v - maxv);
        den += e;
        num += e * v;
    }
    float agg = num / (den + 1e-16f);
    out[(size_t)n * NF + f] = agg + xd[(size_t)n * NF + f];
}

// ---------------- tiled GEMM: out = relu(opt-BN(A @ W^T + bias)) ----------------
// A: [M, KTOT] row-major; W: [J, KTOT] row-major; out: [M, J]
template <int KTOT, bool BN>
__global__ __launch_bounds__(256) void gemm_kernel(const float* __restrict__ A,
                                                   const float* __restrict__ W,
                                                   const float* __restrict__ bias,
                                                   const float* __restrict__ gamma,
                                                   const float* __restrict__ beta,
                                                   float* __restrict__ out, int M, int J) {
    const int KC = 50;
    __shared__ float a_lds[KC][68];
    __shared__ float b_lds[KC][68];
    int tid = threadIdx.x;
    int tx = tid & 15, ty = tid >> 4;
    int n0 = blockIdx.x * 64;
    int j0 = blockIdx.y * 64;
    float acc[4][4] = {};
    for (int k0 = 0; k0 < KTOT; k0 += KC) {
        for (int idx = tid; idx < 64 * KC; idx += 256) {
            int r = idx / KC, k = idx % KC;
            int n = n0 + r;
            a_lds[k][r] = (n < M) ? A[(size_t)n * KTOT + k0 + k] : 0.f;
        }
        for (int idx = tid; idx < 64 * KC; idx += 256) {
            int r = idx / KC, k = idx % KC;
            int j = j0 + r;
            b_lds[k][r] = (j < J) ? W[(size_t)j * KTOT + k0 + k] : 0.f;
        }
        __syncthreads();
        for (int k = 0; k < KC; ++k) {
            float4 av = *(const float4*)&a_lds[k][ty * 4];
            float4 bv = *(const float4*)&b_lds[k][tx * 4];
            float a[4] = {av.x, av.y, av.z, av.w};
            float b[4] = {bv.x, bv.y, bv.z, bv.w};
#pragma unroll
            for (int i = 0; i < 4; ++i)
#pragma unroll
                for (int j = 0; j < 4; ++j) acc[i][j] += a[i] * b[j];
        }
        __syncthreads();
    }
#pragma unroll
    for (int i = 0; i < 4; ++i) {
        int n = n0 + ty * 4 + i;
        if (n >= M) continue;
#pragma unroll
        for (int j = 0; j < 4; ++j) {
            int col = j0 + tx * 4 + j;
            if (col >= J) continue;
            float v = acc[i][j] + bias[col];
            if (BN) v = v * bn_scale(gamma[col]) + beta[col];
            v = fmaxf(v, 0.f);
            out[(size_t)n * J + col] = v;
        }
    }
}

// ---------------- readout (mean/max per graph) ----------------
__global__ __launch_bounds__(256) void readout_kernel(const float* __restrict__ h,
                                                      const int* __restrict__ batch,
                                                      float* __restrict__ sum,
                                                      unsigned* __restrict__ mx, int n_nodes) {
    int idx = blockIdx.x * 256 + threadIdx.x;
    if (idx >= n_nodes * NF) return;
    int n = idx / NF, f = idx % NF;
    float v = h[idx]; // post-ReLU, >= 0
    int g = batch[n];
    atomicAdd(&sum[g * NF + f], v);
    atomicMax(&mx[g * NF + f], __float_as_uint(v));
}

// ---------------- head: encode + fc1 + classifier ----------------
__global__ __launch_bounds__(256) void head_kernel(const float* __restrict__ rbuf,
                                                   const int* __restrict__ cnt,
                                                   const float* __restrict__ fc1w,
                                                   const float* __restrict__ fc1b,
                                                   const float* __restrict__ clsw,
                                                   const float* __restrict__ clsb,
                                                   float* __restrict__ out, int G) {
    __shared__ float enc[HF];
    __shared__ float z[NF];
    int g = blockIdx.x;
    int t = threadIdx.x;
    const float* sum1 = rbuf;
    const float* sum2 = rbuf + (size_t)G * NF;
    const float* sum3 = rbuf + (size_t)2 * G * NF;
    const float* mx1 = rbuf + (size_t)3 * G * NF;
    const float* mx2 = rbuf + (size_t)4 * G * NF;
    const float* mx3 = rbuf + (size_t)5 * G * NF;
    float ic = 1.f / fmaxf((float)cnt[g], 1.f);
    if (t < HF) {
        float e;
        if (t < NF) {
            e = fmaxf(sum1[g * NF + t] * ic, 0.f) + fmaxf(sum2[g * NF + t] * ic, 0.f) +
                fmaxf(sum3[g * NF + t] * ic, 0.f);
        } else {
            int f = t - NF;
            e = fmaxf(mx1[g * NF + f], 0.f) + fmaxf(mx2[g * NF + f], 0.f) +
                fmaxf(mx3[g * NF + f], 0.f);
        }
        enc[t] = e;
        out[G * 2 + (size_t)g * HF + t] = e;
    }
    __syncthreads();
    if (t < NF) {
        float a = fc1b[t];
        for (int k = 0; k < HF; ++k) a += enc[k] * fc1w[t * HF + k];
        z[t] = fmaxf(a, 0.f);
    }
    __syncthreads();
    if (t < 2) {
        float a = clsb[t];
        for (int k = 0; k < NF; ++k) a += z[k] * clsw[t * NF + k];
        out[(size_t)g * 2 + t] = a;
    }
}

extern "C" void kernel_launch(void* const* d_in, const int* in_sizes, int n_in,
                              void* d_out, int out_size, void* d_ws, size_t ws_size,
                              hipStream_t stream) {
    const float* x        = (const float*)d_in[0];
    const int*   eidx     = (const int*)d_in[1];
    const int*   batch    = (const int*)d_in[2];
    const float* c1_src_w = (const float*)d_in[3];
    const float* c1_src_b = (const float*)d_in[4];
    const float* c1_dst_w = (const float*)d_in[5];
    const float* c1_dst_b = (const float*)d_in[6];
    const float* cw1[3] = {(const float*)d_in[7],  (const float*)d_in[13], (const float*)d_in[19]};
    const float* cb1[3] = {(const float*)d_in[8],  (const float*)d_in[14], (const float*)d_in[20]};
    const float* cg[3]  = {(const float*)d_in[9],  (const float*)d_in[15], (const float*)d_in[21]};
    const float* cbe[3] = {(const float*)d_in[10], (const float*)d_in[16], (const float*)d_in[22]};
    const float* cw2[3] = {(const float*)d_in[11], (const float*)d_in[17], (const float*)d_in[23]};
    const float* cb2[3] = {(const float*)d_in[12], (const float*)d_in[18], (const float*)d_in[24]};
    const float* fc1w = (const float*)d_in[25];
    const float* fc1b = (const float*)d_in[26];
    const float* clsw = (const float*)d_in[27];
    const float* clsb = (const float*)d_in[28];

    const int N = in_sizes[0] / XF;
    const int E = in_sizes[1] / 2;
    const int G = out_size / 202;
    const int MC = (N + 1) / 2; // M-chunk for MLP intermediate

    // workspace carve-up
    char* p = (char*)d_ws;
    auto alloc = [&](size_t bytes) {
        char* r = p;
        p += (bytes + 255) & ~(size_t)255;
        return r;
    };
    float* A    = (float*)alloc((size_t)N * NF * 4);
    float* B    = (float*)alloc((size_t)N * NF * 4);
    float* C    = (float*)alloc((size_t)N * NF * 4);
    float* HH   = (float*)alloc((size_t)MC * HF * 4);
    int* indptr  = (int*)alloc((size_t)(N + 1) * 4);
    int* fillpos = (int*)alloc((size_t)(N + 1) * 4);
    int* counts  = (int*)alloc((size_t)N * 4);
    int* incl    = (int*)alloc((size_t)N * 4);
    const int NB = (N + 1023) / 1024;
    int* blocksum = (int*)alloc((size_t)NB * 4);
    int* esrc     = (int*)alloc((size_t)E * 4);
    float* rbuf   = (float*)alloc((size_t)6 * G * NF * 4 + (size_t)G * 4);
    int* cnt = (int*)(rbuf + (size_t)6 * G * NF);

    // zero the accumulators
    hipMemsetAsync(counts, 0, (size_t)N * 4, stream);
    hipMemsetAsync(rbuf, 0, (size_t)6 * G * NF * 4 + (size_t)G * 4, stream);

    // CSR build
    hist_kernel<<<(E + 255) / 256, 256, 0, stream>>>(eidx, counts, E);
    scan1_kernel<<<NB, 256, 0, stream>>>(counts, incl, blocksum, N);
    scan2_kernel<<<1, 64, 0, stream>>>(blocksum, NB);
    scan3_kernel<<<(N + 255) / 256, 256, 0, stream>>>(incl, blocksum, indptr, fillpos, N);
    fill_kernel<<<(E + 255) / 256, 256, 0, stream>>>(eidx, fillpos, esrc, E);
    cnt_kernel<<<(N + 255) / 256, 256, 0, stream>>>(batch, cnt, N);

    // layer-1 input transforms
    lin10_kernel<<<((size_t)N * NF + 255) / 256, 256, 0, stream>>>(x, c1_src_w, c1_src_b,
                                                                   c1_dst_w, c1_dst_b, A, B, N);

    auto run_mlp = [&](int layer, const float* aggout, float* hout) {
        for (int c = 0; c < 2; ++c) {
            int m0 = c * MC;
            int m = (N - m0 < MC) ? (N - m0) : MC;
            if (m <= 0) break;
            dim3 g1((m + 63) / 64, (HF + 63) / 64);
            gemm_kernel<NF, true><<<g1, 256, 0, stream>>>(aggout + (size_t)m0 * NF, cw1[layer],
                                                          cb1[layer], cg[layer], cbe[layer], HH, m, HF);
            dim3 g2((m + 63) / 64, (NF + 63) / 64);
            gemm_kernel<HF, false><<<g2, 256, 0, stream>>>(HH, cw2[layer], cb2[layer], nullptr,
                                                           nullptr, hout + (size_t)m0 * NF, m, NF);
        }
    };

    // layer 1: hsrc=A, xd=B -> agg C -> MLP -> h1 in A
    agg_kernel<<<N, 128, 0, stream>>>(A, B, indptr, esrc, C);
    run_mlp(0, C, A);
    readout_kernel<<<((size_t)N * NF + 255) / 256, 256, 0, stream>>>(
        A, batch, rbuf + (size_t)0 * G * NF, (unsigned*)(rbuf + (size_t)3 * G * NF), N);

    // layer 2: h1=A -> agg C -> MLP -> h2 in B
    agg_kernel<<<N, 128, 0, stream>>>(A, A, indptr, esrc, C);
    run_mlp(1, C, B);
    readout_kernel<<<((size_t)N * NF + 255) / 256, 256, 0, stream>>>(
        B, batch, rbuf + (size_t)1 * G * NF, (unsigned*)(rbuf + (size_t)4 * G * NF), N);

    // layer 3: h2=B -> agg C -> MLP -> h3 in A (h1 dead)
    agg_kernel<<<N, 128, 0, stream>>>(B, B, indptr, esrc, C);
    run_mlp(2, C, A);
    readout_kernel<<<((size_t)N * NF + 255) / 256, 256, 0, stream>>>(
        A, batch, rbuf + (size_t)2 * G * NF, (unsigned*)(rbuf + (size_t)5 * G * NF), N);

    // head
    head_kernel<<<G, 256, 0, stream>>>(rbuf, cnt, fc1w, fc1b, clsw, clsb, (float*)d_out, G);
}

// Round 2
// 2307.068 us; speedup vs baseline: 8.9502x; 8.9502x over previous
//
#include <hip/hip_runtime.h>
#include <cstdint>
#include <cstddef>

#define XF 10
#define NF 100
#define HF 200

static __device__ __forceinline__ float bn_scale(float g) {
    return g * 0.9999950000374997f; // 1/sqrt(1 + 1e-5)
}

// ---------------- CSR build ----------------
__global__ __launch_bounds__(256) void hist_kernel(const int* __restrict__ eidx,
                                                   int* __restrict__ counts, int E) {
    int e = blockIdx.x * 256 + threadIdx.x;
    if (e < E) atomicAdd(&counts[eidx[E + e]], 1);
}

__global__ __launch_bounds__(256) void scan1_kernel(const int* __restrict__ counts,
                                                    int* __restrict__ incl,
                                                    int* __restrict__ blocksum, int n) {
    __shared__ int s[256];
    int t = threadIdx.x;
    int base = blockIdx.x * 1024 + t * 4;
    int v0 = (base + 0 < n) ? counts[base + 0] : 0;
    int v1 = (base + 1 < n) ? counts[base + 1] : 0;
    int v2 = (base + 2 < n) ? counts[base + 2] : 0;
    int v3 = (base + 3 < n) ? counts[base + 3] : 0;
    int tot = v0 + v1 + v2 + v3;
    s[t] = tot;
    __syncthreads();
    for (int off = 1; off < 256; off <<= 1) {
        int add = (t >= off) ? s[t - off] : 0;
        __syncthreads();
        s[t] += add;
        __syncthreads();
    }
    int run = s[t] - tot;
    run += v0; if (base + 0 < n) incl[base + 0] = run;
    run += v1; if (base + 1 < n) incl[base + 1] = run;
    run += v2; if (base + 2 < n) incl[base + 2] = run;
    run += v3; if (base + 3 < n) incl[base + 3] = run;
    if (t == 255) blocksum[blockIdx.x] = s[255];
}

__global__ void scan2_kernel(int* __restrict__ blocksum, int nb) {
    if (blockIdx.x == 0 && threadIdx.x == 0) {
        int r = 0;
        for (int i = 0; i < nb; ++i) { int t = blocksum[i]; blocksum[i] = r; r += t; }
    }
}

__global__ __launch_bounds__(256) void scan3_kernel(const int* __restrict__ incl,
                                                    const int* __restrict__ blockoff,
                                                    int* __restrict__ indptr,
                                                    int* __restrict__ fillpos, int n) {
    int i = blockIdx.x * 256 + threadIdx.x;
    if (i >= n) return;
    int v = incl[i] + blockoff[i >> 10];
    indptr[i + 1] = v;
    fillpos[i + 1] = v;
    if (i == 0) { indptr[0] = 0; fillpos[0] = 0; }
}

__global__ __launch_bounds__(256) void fill_kernel(const int* __restrict__ eidx,
                                                   int* __restrict__ fillpos,
                                                   int* __restrict__ esrc, int E) {
    int e = blockIdx.x * 256 + threadIdx.x;
    if (e >= E) return;
    int d = eidx[E + e];
    int p = atomicAdd(&fillpos[d], 1);
    esrc[p] = eidx[e];
}

__global__ __launch_bounds__(256) void cnt_kernel(const int* __restrict__ batch,
                                                  int* __restrict__ cnt, int n) {
    int i = blockIdx.x * 256 + threadIdx.x;
    if (i < n) atomicAdd(&cnt[batch[i]], 1);
}

// ---------------- layer-1 input linear (10 -> 100, src & dst) ----------------
__global__ __launch_bounds__(256) void lin10_kernel(const float* __restrict__ x,
                                                    const float* __restrict__ sw,
                                                    const float* __restrict__ sb,
                                                    const float* __restrict__ dw,
                                                    const float* __restrict__ db,
                                                    float* __restrict__ hsrc,
                                                    float* __restrict__ xd, int n_nodes) {
    int idx = blockIdx.x * 256 + threadIdx.x;
    if (idx >= n_nodes * NF) return;
    int n = idx / NF, f = idx % NF;
    float xv[XF];
#pragma unroll
    for (int k = 0; k < XF; ++k) xv[k] = x[n * XF + k];
    float a = sb[f], b = db[f];
#pragma unroll
    for (int k = 0; k < XF; ++k) {
        a += xv[k] * sw[f * XF + k];
        b += xv[k] * dw[f * XF + k];
    }
    hsrc[idx] = a;
    xd[idx] = b;
}

// ---------------- softmax aggregation (GENConv) ----------------
__global__ __launch_bounds__(128) void agg_kernel(const float* __restrict__ h,
                                                  const float* __restrict__ xd,
                                                  const int* __restrict__ indptr,
                                                  const int* __restrict__ esrc,
                                                  float* __restrict__ out) {
    int n = blockIdx.x;
    int f = threadIdx.x;
    if (f >= NF) return;
    int beg = indptr[n], end = indptr[n + 1];
    float maxv = 0.f;
    for (int j = beg; j < end; ++j) {
        int s = esrc[j];
        float v = fmaxf(h[(size_t)s * NF + f], 0.f) + 1e-7f;
        maxv = fmaxf(maxv, v);
    }
    float den = 0.f, num = 0.f;
    for (int j = beg; j < end; ++j) {
        int s = esrc[j];
        float v = fmaxf(h[(size_t)s * NF + f], 0.f) + 1e-7f;
        float e = __expf(v - maxv);
        den += e;
        num += e * v;
    }
    float agg = num / (den + 1e-16f);
    out[(size_t)n * NF + f] = agg + xd[(size_t)n * NF + f];
}

// ---------------- tiled GEMM: out = relu(opt-BN(A @ W^T + bias)) ----------------
// A: [M, KTOT] row-major; W: [J, KTOT] row-major; out: [M, J]
// __launch_bounds__(256,4): cap VGPR<=128 (4 blocks/CU); limited unroll avoids
// the round-1 catastrophe (full KC=50 unroll -> 256 VGPR + 5.4 GB spill traffic).
template <int KTOT, bool BN>
__global__ __launch_bounds__(256, 4) void gemm_kernel(const float* __restrict__ A,
                                                      const float* __restrict__ W,
                                                      const float* __restrict__ bias,
                                                      const float* __restrict__ gamma,
                                                      const float* __restrict__ beta,
                                                      float* __restrict__ out, int M, int J) {
    const int KC = 50;
    __shared__ float a_lds[KC][68];
    __shared__ float b_lds[KC][68];
    int tid = threadIdx.x;
    int tx = tid & 15, ty = tid >> 4;
    int n0 = blockIdx.x * 64;
    int j0 = blockIdx.y * 64;
    float acc[4][4] = {};
    for (int k0 = 0; k0 < KTOT; k0 += KC) {
        for (int idx = tid; idx < 64 * KC; idx += 256) {
            int r = idx / KC, k = idx % KC;
            int n = n0 + r;
            a_lds[k][r] = (n < M) ? A[(size_t)n * KTOT + k0 + k] : 0.f;
        }
        for (int idx = tid; idx < 64 * KC; idx += 256) {
            int r = idx / KC, k = idx % KC;
            int j = j0 + r;
            b_lds[k][r] = (j < J) ? W[(size_t)j * KTOT + k0 + k] : 0.f;
        }
        __syncthreads();
#pragma unroll 5
        for (int k = 0; k < KC; ++k) {
            float4 av = *(const float4*)&a_lds[k][ty * 4];
            float4 bv = *(const float4*)&b_lds[k][tx * 4];
            float a[4] = {av.x, av.y, av.z, av.w};
            float b[4] = {bv.x, bv.y, bv.z, bv.w};
#pragma unroll
            for (int i = 0; i < 4; ++i)
#pragma unroll
                for (int j = 0; j < 4; ++j) acc[i][j] += a[i] * b[j];
        }
        __syncthreads();
    }
#pragma unroll
    for (int i = 0; i < 4; ++i) {
        int n = n0 + ty * 4 + i;
        if (n >= M) continue;
#pragma unroll
        for (int j = 0; j < 4; ++j) {
            int col = j0 + tx * 4 + j;
            if (col >= J) continue;
            float v = acc[i][j] + bias[col];
            if (BN) v = v * bn_scale(gamma[col]) + beta[col];
            v = fmaxf(v, 0.f);
            out[(size_t)n * J + col] = v;
        }
    }
}

// ---------------- readout (mean/max per graph) ----------------
__global__ __launch_bounds__(256) void readout_kernel(const float* __restrict__ h,
                                                      const int* __restrict__ batch,
                                                      float* __restrict__ sum,
                                                      unsigned* __restrict__ mx, int n_nodes) {
    int idx = blockIdx.x * 256 + threadIdx.x;
    if (idx >= n_nodes * NF) return;
    int n = idx / NF, f = idx % NF;
    float v = h[idx]; // post-ReLU, >= 0
    int g = batch[n];
    atomicAdd(&sum[g * NF + f], v);
    atomicMax(&mx[g * NF + f], __float_as_uint(v));
}

// ---------------- head: encode + fc1 + classifier ----------------
__global__ __launch_bounds__(256) void head_kernel(const float* __restrict__ rbuf,
                                                   const int* __restrict__ cnt,
                                                   const float* __restrict__ fc1w,
                                                   const float* __restrict__ fc1b,
                                                   const float* __restrict__ clsw,
                                                   const float* __restrict__ clsb,
                                                   float* __restrict__ out, int G) {
    __shared__ float enc[HF];
    __shared__ float z[NF];
    int g = blockIdx.x;
    int t = threadIdx.x;
    const float* sum1 = rbuf;
    const float* sum2 = rbuf + (size_t)G * NF;
    const float* sum3 = rbuf + (size_t)2 * G * NF;
    const float* mx1 = rbuf + (size_t)3 * G * NF;
    const float* mx2 = rbuf + (size_t)4 * G * NF;
    const float* mx3 = rbuf + (size_t)5 * G * NF;
    float ic = 1.f / fmaxf((float)cnt[g], 1.f);
    if (t < HF) {
        float e;
        if (t < NF) {
            e = fmaxf(sum1[g * NF + t] * ic, 0.f) + fmaxf(sum2[g * NF + t] * ic, 0.f) +
                fmaxf(sum3[g * NF + t] * ic, 0.f);
        } else {
            int f = t - NF;
            e = fmaxf(mx1[g * NF + f], 0.f) + fmaxf(mx2[g * NF + f], 0.f) +
                fmaxf(mx3[g * NF + f], 0.f);
        }
        enc[t] = e;
        out[G * 2 + (size_t)g * HF + t] = e;
    }
    __syncthreads();
    if (t < NF) {
        float a = fc1b[t];
        for (int k = 0; k < HF; ++k) a += enc[k] * fc1w[t * HF + k];
        z[t] = fmaxf(a, 0.f);
    }
    __syncthreads();
    if (t < 2) {
        float a = clsb[t];
        for (int k = 0; k < NF; ++k) a += z[k] * clsw[t * NF + k];
        out[(size_t)g * 2 + t] = a;
    }
}

extern "C" void kernel_launch(void* const* d_in, const int* in_sizes, int n_in,
                              void* d_out, int out_size, void* d_ws, size_t ws_size,
                              hipStream_t stream) {
    const float* x        = (const float*)d_in[0];
    const int*   eidx     = (const int*)d_in[1];
    const int*   batch    = (const int*)d_in[2];
    const float* c1_src_w = (const float*)d_in[3];
    const float* c1_src_b = (const float*)d_in[4];
    const float* c1_dst_w = (const float*)d_in[5];
    const float* c1_dst_b = (const float*)d_in[6];
    const float* cw1[3] = {(const float*)d_in[7],  (const float*)d_in[13], (const float*)d_in[19]};
    const float* cb1[3] = {(const float*)d_in[8],  (const float*)d_in[14], (const float*)d_in[20]};
    const float* cg[3]  = {(const float*)d_in[9],  (const float*)d_in[15], (const float*)d_in[21]};
    const float* cbe[3] = {(const float*)d_in[10], (const float*)d_in[16], (const float*)d_in[22]};
    const float* cw2[3] = {(const float*)d_in[11], (const float*)d_in[17], (const float*)d_in[23]};
    const float* cb2[3] = {(const float*)d_in[12], (const float*)d_in[18], (const float*)d_in[24]};
    const float* fc1w = (const float*)d_in[25];
    const float* fc1b = (const float*)d_in[26];
    const float* clsw = (const float*)d_in[27];
    const float* clsb = (const float*)d_in[28];

    const int N = in_sizes[0] / XF;
    const int E = in_sizes[1] / 2;
    const int G = out_size / 202;
    const int NB = (N + 1023) / 1024;

    // workspace carve-up (fixed part first, then HH sized to what's left)
    char* p = (char*)d_ws;
    auto alloc = [&](size_t bytes) {
        char* r = p;
        p += (bytes + 255) & ~(size_t)255;
        return r;
    };
    float* A    = (float*)alloc((size_t)N * NF * 4);
    float* B    = (float*)alloc((size_t)N * NF * 4);
    float* C    = (float*)alloc((size_t)N * NF * 4);
    int* indptr  = (int*)alloc((size_t)(N + 1) * 4);
    int* fillpos = (int*)alloc((size_t)(N + 1) * 4);
    int* counts  = (int*)alloc((size_t)N * 4);
    int* incl    = (int*)alloc((size_t)N * 4);
    int* blocksum = (int*)alloc((size_t)NB * 4);
    int* esrc     = (int*)alloc((size_t)E * 4);
    float* rbuf   = (float*)alloc((size_t)6 * G * NF * 4 + (size_t)G * 4);
    int* cnt = (int*)(rbuf + (size_t)6 * G * NF);
    // HH intermediate: use the remaining workspace; chunk M accordingly
    size_t used = (size_t)(p - (char*)d_ws);
    size_t remain = (ws_size > used + 4096) ? (ws_size - used - 4096) : 0;
    int MC = (int)(remain / ((size_t)HF * 4));
    if (MC > N) MC = N;
    if (MC < 4096) MC = 4096; // floor; round-1 config (N/2) fit, so this is safe
    float* HH = (float*)alloc((size_t)MC * HF * 4);

    hipMemsetAsync(counts, 0, (size_t)N * 4, stream);
    hipMemsetAsync(rbuf, 0, (size_t)6 * G * NF * 4 + (size_t)G * 4, stream);

    // CSR build
    hist_kernel<<<(E + 255) / 256, 256, 0, stream>>>(eidx, counts, E);
    scan1_kernel<<<NB, 256, 0, stream>>>(counts, incl, blocksum, N);
    scan2_kernel<<<1, 64, 0, stream>>>(blocksum, NB);
    scan3_kernel<<<(N + 255) / 256, 256, 0, stream>>>(incl, blocksum, indptr, fillpos, N);
    fill_kernel<<<(E + 255) / 256, 256, 0, stream>>>(eidx, fillpos, esrc, E);
    cnt_kernel<<<(N + 255) / 256, 256, 0, stream>>>(batch, cnt, N);

    // layer-1 input transforms
    lin10_kernel<<<((size_t)N * NF + 255) / 256, 256, 0, stream>>>(x, c1_src_w, c1_src_b,
                                                                   c1_dst_w, c1_dst_b, A, B, N);

    auto run_mlp = [&](int layer, const float* aggout, float* hout) {
        for (int m0 = 0; m0 < N; m0 += MC) {
            int m = (N - m0 < MC) ? (N - m0) : MC;
            dim3 g1((m + 63) / 64, (HF + 63) / 64);
            gemm_kernel<NF, true><<<g1, 256, 0, stream>>>(aggout + (size_t)m0 * NF, cw1[layer],
                                                          cb1[layer], cg[layer], cbe[layer], HH, m, HF);
            dim3 g2((m + 63) / 64, (NF + 63) / 64);
            gemm_kernel<HF, false><<<g2, 256, 0, stream>>>(HH, cw2[layer], cb2[layer], nullptr,
                                                           nullptr, hout + (size_t)m0 * NF, m, NF);
        }
    };

    // layer 1
    agg_kernel<<<N, 128, 0, stream>>>(A, B, indptr, esrc, C);
    run_mlp(0, C, A);
    readout_kernel<<<((size_t)N * NF + 255) / 256, 256, 0, stream>>>(
        A, batch, rbuf + (size_t)0 * G * NF, (unsigned*)(rbuf + (size_t)3 * G * NF), N);

    // layer 2
    agg_kernel<<<N, 128, 0, stream>>>(A, A, indptr, esrc, C);
    run_mlp(1, C, B);
    readout_kernel<<<((size_t)N * NF + 255) / 256, 256, 0, stream>>>(
        B, batch, rbuf + (size_t)1 * G * NF, (unsigned*)(rbuf + (size_t)4 * G * NF), N);

    // layer 3
    agg_kernel<<<N, 128, 0, stream>>>(B, B, indptr, esrc, C);
    run_mlp(2, C, A);
    readout_kernel<<<((size_t)N * NF + 255) / 256, 256, 0, stream>>>(
        A, batch, rbuf + (size_t)2 * G * NF, (unsigned*)(rbuf + (size_t)5 * G * NF), N);

    // head
    head_kernel<<<G, 256, 0, stream>>>(rbuf, cnt, fc1w, fc1b, clsw, clsb, (float*)d_out, G);
}

// Round 3
// 1369.167 us; speedup vs baseline: 15.0813x; 1.6850x over previous
//
#include <hip/hip_runtime.h>
#include <cstdint>
#include <cstddef>

#define XF 10
#define NF 100
#define HF 200

typedef _Float16 f16x8 __attribute__((ext_vector_type(8)));
typedef _Float16 h2 __attribute__((ext_vector_type(2)));
typedef float f32x4 __attribute__((ext_vector_type(4)));

static __device__ __forceinline__ float bn_scale(float g) {
    return g * 0.9999950000374997f; // 1/sqrt(1 + 1e-5)
}

// ---------------- CSR build ----------------
__global__ __launch_bounds__(256) void hist_kernel(const int* __restrict__ eidx,
                                                   int* __restrict__ counts, int E) {
    int e = blockIdx.x * 256 + threadIdx.x;
    if (e < E) atomicAdd(&counts[eidx[E + e]], 1);
}

__global__ __launch_bounds__(256) void scan1_kernel(const int* __restrict__ counts,
                                                    int* __restrict__ incl,
                                                    int* __restrict__ blocksum, int n) {
    __shared__ int s[256];
    int t = threadIdx.x;
    int base = blockIdx.x * 1024 + t * 4;
    int v0 = (base + 0 < n) ? counts[base + 0] : 0;
    int v1 = (base + 1 < n) ? counts[base + 1] : 0;
    int v2 = (base + 2 < n) ? counts[base + 2] : 0;
    int v3 = (base + 3 < n) ? counts[base + 3] : 0;
    int tot = v0 + v1 + v2 + v3;
    s[t] = tot;
    __syncthreads();
    for (int off = 1; off < 256; off <<= 1) {
        int add = (t >= off) ? s[t - off] : 0;
        __syncthreads();
        s[t] += add;
        __syncthreads();
    }
    int run = s[t] - tot;
    run += v0; if (base + 0 < n) incl[base + 0] = run;
    run += v1; if (base + 1 < n) incl[base + 1] = run;
    run += v2; if (base + 2 < n) incl[base + 2] = run;
    run += v3; if (base + 3 < n) incl[base + 3] = run;
    if (t == 255) blocksum[blockIdx.x] = s[255];
}

__global__ void scan2_kernel(int* __restrict__ blocksum, int nb) {
    if (blockIdx.x == 0 && threadIdx.x == 0) {
        int r = 0;
        for (int i = 0; i < nb; ++i) { int t = blocksum[i]; blocksum[i] = r; r += t; }
    }
}

__global__ __launch_bounds__(256) void scan3_kernel(const int* __restrict__ incl,
                                                    const int* __restrict__ blockoff,
                                                    int* __restrict__ indptr,
                                                    int* __restrict__ fillpos, int n) {
    int i = blockIdx.x * 256 + threadIdx.x;
    if (i >= n) return;
    int v = incl[i] + blockoff[i >> 10];
    indptr[i + 1] = v;
    fillpos[i + 1] = v;
    if (i == 0) { indptr[0] = 0; fillpos[0] = 0; }
}

__global__ __launch_bounds__(256) void fill_kernel(const int* __restrict__ eidx,
                                                   int* __restrict__ fillpos,
                                                   int* __restrict__ esrc, int E) {
    int e = blockIdx.x * 256 + threadIdx.x;
    if (e >= E) return;
    int d = eidx[E + e];
    int p = atomicAdd(&fillpos[d], 1);
    esrc[p] = eidx[e];
}

__global__ __launch_bounds__(256) void cnt_kernel(const int* __restrict__ batch,
                                                  int* __restrict__ cnt, int n) {
    int i = blockIdx.x * 256 + threadIdx.x;
    if (i < n) atomicAdd(&cnt[batch[i]], 1);
}

// ---------------- weight conversion to fp16, K padded ----------------
// w<3: [200x100] -> [256x128] ; w>=3: [100x200] -> [128x256]; pad = 0
struct WArgs {
    const float* src[6];
    _Float16* dst[6];
};
__global__ __launch_bounds__(256) void wconv_kernel(WArgs wa) {
    int w = blockIdx.y;
    int idx = blockIdx.x * 256 + threadIdx.x; // < 32768
    int J, K, j, k;
    if (w < 3) { J = 200; K = 100; j = idx >> 7; k = idx & 127; }
    else       { J = 100; K = 200; j = idx >> 8; k = idx & 255; }
    float v = (j < J && k < K) ? wa.src[w][j * K + k] : 0.f;
    wa.dst[w][idx] = (_Float16)v;
}

// ---------------- layer-1 input linear (10 -> 100) -> fp16, stride 128 ---------
__global__ __launch_bounds__(256) void lin10_kernel(const float* __restrict__ x,
                                                    const float* __restrict__ sw,
                                                    const float* __restrict__ sb,
                                                    const float* __restrict__ dw,
                                                    const float* __restrict__ db,
                                                    _Float16* __restrict__ h16,
                                                    _Float16* __restrict__ xd16, int n_nodes) {
    int idx = blockIdx.x * 256 + threadIdx.x;
    if (idx >= n_nodes * 64) return;
    int n = idx >> 6, f2 = idx & 63;
    float a0 = 0.f, a1 = 0.f, b0 = 0.f, b1 = 0.f;
    if (f2 < 50) {
        int f0 = 2 * f2, f1 = 2 * f2 + 1;
        float xv[XF];
#pragma unroll
        for (int k = 0; k < XF; ++k) xv[k] = x[n * XF + k];
        a0 = sb[f0]; a1 = sb[f1]; b0 = db[f0]; b1 = db[f1];
#pragma unroll
        for (int k = 0; k < XF; ++k) {
            a0 += xv[k] * sw[f0 * XF + k];
            a1 += xv[k] * sw[f1 * XF + k];
            b0 += xv[k] * dw[f0 * XF + k];
            b1 += xv[k] * dw[f1 * XF + k];
        }
    }
    ((h2*)(h16 + (size_t)n * 128))[f2] = (h2){(_Float16)a0, (_Float16)a1};
    ((h2*)(xd16 + (size_t)n * 128))[f2] = (h2){(_Float16)b0, (_Float16)b1};
}

// ---------------- softmax aggregation: 1 wave per node, online softmax --------
// gather rows of h16 (fp16, stride 128, pad cols are 0); 2 features per lane
__global__ __launch_bounds__(128) void agg_kernel(const _Float16* __restrict__ h16,
                                                  const _Float16* __restrict__ xd16,
                                                  const int* __restrict__ indptr,
                                                  const int* __restrict__ esrc,
                                                  _Float16* __restrict__ c16, int n_nodes) {
    int n = blockIdx.x * 2 + (threadIdx.x >> 6);
    if (n >= n_nodes) return;
    int lane = threadIdx.x & 63;
    int beg = __builtin_amdgcn_readfirstlane(indptr[n]);
    int end = __builtin_amdgcn_readfirstlane(indptr[n + 1]);
    const h2* hb = (const h2*)h16;
    float m0 = 0.f, m1 = 0.f, d0 = 0.f, d1 = 0.f, s0 = 0.f, s1 = 0.f;
    h2 cur = (h2){(_Float16)0.f, (_Float16)0.f};
    if (beg < end) {
        int s = esrc[beg];
        cur = hb[(size_t)s * 64 + lane];
    }
    for (int j = beg; j < end; ++j) {
        h2 nxt = cur;
        if (j + 1 < end) {
            int s2 = esrc[j + 1];
            nxt = hb[(size_t)s2 * 64 + lane];
        }
        float v0 = (float)cur.x, v1 = (float)cur.y;
        float a0 = fmaxf(v0, 0.f) + 1e-7f;
        float a1 = fmaxf(v1, 0.f) + 1e-7f;
        float nm0 = fmaxf(m0, a0), nm1 = fmaxf(m1, a1);
        float sc0 = __expf(m0 - nm0), e0 = __expf(a0 - nm0);
        float sc1 = __expf(m1 - nm1), e1 = __expf(a1 - nm1);
        d0 = d0 * sc0 + e0; s0 = s0 * sc0 + e0 * a0; m0 = nm0;
        d1 = d1 * sc1 + e1; s1 = s1 * sc1 + e1 * a1; m1 = nm1;
        cur = nxt;
    }
    float g0 = s0 / (d0 + 1e-16f);
    float g1 = s1 / (d1 + 1e-16f);
    float o0 = 0.f, o1 = 0.f;
    if (lane < 50) {
        h2 xv = ((const h2*)(xd16 + (size_t)n * 128))[lane];
        o0 = g0 + (float)xv.x;
        o1 = g1 + (float)xv.y;
    }
    ((h2*)(c16 + (size_t)n * 128))[lane] = (h2){(_Float16)o0, (_Float16)o1};
}

// ---------------- MFMA f16 GEMM: out16 = relu(opt-BN(A @ W^T + bias)) ---------
// A: [Mpad, LDA] fp16 (K padded w/ zeros); W: [Jpad, LDA] fp16 (zero-padded rows/cols)
// block = 4 waves; block tile 64 rows x 64 cols; wave tile 64x16 (4 MFMA accs)
template <int KSTEPS, int LDA, bool BN>
__global__ __launch_bounds__(256, 4) void mfma_gemm_kernel(const _Float16* __restrict__ A,
                                                           const _Float16* __restrict__ W,
                                                           const float* __restrict__ bias,
                                                           const float* __restrict__ gamma,
                                                           const float* __restrict__ beta,
                                                           _Float16* __restrict__ out16,
                                                           int ldo, int M, int J) {
    int wave = threadIdx.x >> 6;
    int lane = threadIdx.x & 63;
    int l15 = lane & 15, quad = lane >> 4;
    long m0 = (long)blockIdx.x * 64;
    int j0 = blockIdx.y * 64 + wave * 16;
    const _Float16* aptr = A + (m0 + l15) * LDA + quad * 8;
    const _Float16* wptr = W + (size_t)(j0 + l15) * LDA + quad * 8;
    f32x4 acc0 = {0.f, 0.f, 0.f, 0.f}, acc1 = acc0, acc2 = acc0, acc3 = acc0;
#pragma unroll 2
    for (int ks = 0; ks < KSTEPS; ++ks) {
        f16x8 b  = *(const f16x8*)(wptr + ks * 32);
        f16x8 a0 = *(const f16x8*)(aptr + ks * 32);
        f16x8 a1 = *(const f16x8*)(aptr + 16 * LDA + ks * 32);
        f16x8 a2 = *(const f16x8*)(aptr + 32 * LDA + ks * 32);
        f16x8 a3 = *(const f16x8*)(aptr + 48 * LDA + ks * 32);
        acc0 = __builtin_amdgcn_mfma_f32_16x16x32_f16(a0, b, acc0, 0, 0, 0);
        acc1 = __builtin_amdgcn_mfma_f32_16x16x32_f16(a1, b, acc1, 0, 0, 0);
        acc2 = __builtin_amdgcn_mfma_f32_16x16x32_f16(a2, b, acc2, 0, 0, 0);
        acc3 = __builtin_amdgcn_mfma_f32_16x16x32_f16(a3, b, acc3, 0, 0, 0);
    }
    int col = j0 + l15;
    bool cv = col < J;
    float bi = cv ? bias[col] : 0.f;
    float gm = 1.f, bt = 0.f;
    if (BN && cv) { gm = bn_scale(gamma[col]); bt = beta[col]; }
    f32x4 accs[4] = {acc0, acc1, acc2, acc3};
#pragma unroll
    for (int i = 0; i < 4; ++i) {
#pragma unroll
        for (int r = 0; r < 4; ++r) {
            long row = m0 + i * 16 + quad * 4 + r;
            float v = accs[i][r] + bi;
            if (BN) v = v * gm + bt;
            v = fmaxf(v, 0.f);
            if (!cv) v = 0.f;
            if (row < M) out16[row * ldo + col] = (_Float16)v;
        }
    }
}

// ---------------- readout (mean/max per graph) from fp16 h --------------------
__global__ __launch_bounds__(256) void readout_kernel(const _Float16* __restrict__ h16,
                                                      const int* __restrict__ batch,
                                                      float* __restrict__ sum,
                                                      unsigned* __restrict__ mx, int n_nodes) {
    int idx = blockIdx.x * 256 + threadIdx.x;
    if (idx >= n_nodes * 128) return;
    int n = idx >> 7, f = idx & 127;
    if (f >= NF) return;
    float v = (float)h16[idx]; // post-ReLU, >= 0
    int g = batch[n];
    atomicAdd(&sum[g * NF + f], v);
    atomicMax(&mx[g * NF + f], __float_as_uint(v));
}

// ---------------- head: encode + fc1 + classifier ----------------
__global__ __launch_bounds__(256) void head_kernel(const float* __restrict__ rbuf,
                                                   const int* __restrict__ cnt,
                                                   const float* __restrict__ fc1w,
                                                   const float* __restrict__ fc1b,
                                                   const float* __restrict__ clsw,
                                                   const float* __restrict__ clsb,
                                                   float* __restrict__ out, int G) {
    __shared__ float enc[HF];
    __shared__ float z[NF];
    int g = blockIdx.x;
    int t = threadIdx.x;
    const float* sum1 = rbuf;
    const float* sum2 = rbuf + (size_t)G * NF;
    const float* sum3 = rbuf + (size_t)2 * G * NF;
    const float* mx1 = rbuf + (size_t)3 * G * NF;
    const float* mx2 = rbuf + (size_t)4 * G * NF;
    const float* mx3 = rbuf + (size_t)5 * G * NF;
    float ic = 1.f / fmaxf((float)cnt[g], 1.f);
    if (t < HF) {
        float e;
        if (t < NF) {
            e = fmaxf(sum1[g * NF + t] * ic, 0.f) + fmaxf(sum2[g * NF + t] * ic, 0.f) +
                fmaxf(sum3[g * NF + t] * ic, 0.f);
        } else {
            int f = t - NF;
            e = fmaxf(mx1[g * NF + f], 0.f) + fmaxf(mx2[g * NF + f], 0.f) +
                fmaxf(mx3[g * NF + f], 0.f);
        }
        enc[t] = e;
        out[G * 2 + (size_t)g * HF + t] = e;
    }
    __syncthreads();
    if (t < NF) {
        float a = fc1b[t];
        for (int k = 0; k < HF; ++k) a += enc[k] * fc1w[t * HF + k];
        z[t] = fmaxf(a, 0.f);
    }
    __syncthreads();
    if (t < 2) {
        float a = clsb[t];
        for (int k = 0; k < NF; ++k) a += z[k] * clsw[t * NF + k];
        out[(size_t)g * 2 + t] = a;
    }
}

extern "C" void kernel_launch(void* const* d_in, const int* in_sizes, int n_in,
                              void* d_out, int out_size, void* d_ws, size_t ws_size,
                              hipStream_t stream) {
    const float* x        = (const float*)d_in[0];
    const int*   eidx     = (const int*)d_in[1];
    const int*   batch    = (const int*)d_in[2];
    const float* c1_src_w = (const float*)d_in[3];
    const float* c1_src_b = (const float*)d_in[4];
    const float* c1_dst_w = (const float*)d_in[5];
    const float* c1_dst_b = (const float*)d_in[6];
    const float* cw1[3] = {(const float*)d_in[7],  (const float*)d_in[13], (const float*)d_in[19]};
    const float* cb1[3] = {(const float*)d_in[8],  (const float*)d_in[14], (const float*)d_in[20]};
    const float* cg[3]  = {(const float*)d_in[9],  (const float*)d_in[15], (const float*)d_in[21]};
    const float* cbe[3] = {(const float*)d_in[10], (const float*)d_in[16], (const float*)d_in[22]};
    const float* cw2[3] = {(const float*)d_in[11], (const float*)d_in[17], (const float*)d_in[23]};
    const float* cb2[3] = {(const float*)d_in[12], (const float*)d_in[18], (const float*)d_in[24]};
    const float* fc1w = (const float*)d_in[25];
    const float* fc1b = (const float*)d_in[26];
    const float* clsw = (const float*)d_in[27];
    const float* clsb = (const float*)d_in[28];

    const int N = in_sizes[0] / XF;
    const int E = in_sizes[1] / 2;
    const int G = out_size / 202;
    const int NB = (N + 1023) / 1024;
    const int Mpad = (N + 63) & ~63;

    char* p = (char*)d_ws;
    auto alloc = [&](size_t bytes) {
        char* r = p;
        p += (bytes + 255) & ~(size_t)255;
        return r;
    };
    _Float16* h16  = (_Float16*)alloc((size_t)Mpad * 128 * 2);
    _Float16* C16  = (_Float16*)alloc((size_t)Mpad * 128 * 2);
    _Float16* HH16 = (_Float16*)alloc((size_t)Mpad * 256 * 2);
    _Float16* xd16 = HH16; // alias: xd16 dead before gemm1 writes HH16
    _Float16* W16  = (_Float16*)alloc((size_t)6 * 32768 * 2);
    int* indptr   = (int*)alloc((size_t)(N + 1) * 4);
    int* fillpos  = (int*)alloc((size_t)(N + 1) * 4);
    int* counts   = (int*)alloc((size_t)N * 4);
    int* incl     = (int*)alloc((size_t)N * 4);
    int* blocksum = (int*)alloc((size_t)NB * 4);
    int* esrc     = (int*)alloc((size_t)E * 4);
    float* rbuf   = (float*)alloc((size_t)6 * G * NF * 4 + (size_t)G * 4);
    int* cnt = (int*)(rbuf + (size_t)6 * G * NF);

    hipMemsetAsync(counts, 0, (size_t)N * 4, stream);
    hipMemsetAsync(rbuf, 0, (size_t)6 * G * NF * 4 + (size_t)G * 4, stream);

    // CSR build
    hist_kernel<<<(E + 255) / 256, 256, 0, stream>>>(eidx, counts, E);
    scan1_kernel<<<NB, 256, 0, stream>>>(counts, incl, blocksum, N);
    scan2_kernel<<<1, 64, 0, stream>>>(blocksum, NB);
    scan3_kernel<<<(N + 255) / 256, 256, 0, stream>>>(incl, blocksum, indptr, fillpos, N);
    fill_kernel<<<(E + 255) / 256, 256, 0, stream>>>(eidx, fillpos, esrc, E);
    cnt_kernel<<<(N + 255) / 256, 256, 0, stream>>>(batch, cnt, N);

    // weights -> fp16 (padded)
    WArgs wa;
    for (int l = 0; l < 3; ++l) {
        wa.src[l] = cw1[l];     wa.dst[l] = W16 + (size_t)l * 32768;
        wa.src[3 + l] = cw2[l]; wa.dst[3 + l] = W16 + (size_t)(3 + l) * 32768;
    }
    wconv_kernel<<<dim3(128, 6), 256, 0, stream>>>(wa);

    // layer-1 input transforms (h16 = x@src_w pre-relu; xd16 = x@dst_w)
    lin10_kernel<<<((size_t)N * 64 + 255) / 256, 256, 0, stream>>>(x, c1_src_w, c1_src_b,
                                                                   c1_dst_w, c1_dst_b, h16, xd16, N);

    const float* h0 = nullptr;
    for (int l = 0; l < 3; ++l) {
        const _Float16* xdp = (l == 0) ? xd16 : h16;
        agg_kernel<<<(N + 1) / 2, 128, 0, stream>>>(h16, xdp, indptr, esrc, C16, N);
        mfma_gemm_kernel<4, 128, true><<<dim3(Mpad / 64, 4), 256, 0, stream>>>(
            C16, W16 + (size_t)l * 32768, cb1[l], cg[l], cbe[l], HH16, 256, N, HF);
        mfma_gemm_kernel<8, 256, false><<<dim3(Mpad / 64, 2), 256, 0, stream>>>(
            HH16, W16 + (size_t)(3 + l) * 32768, cb2[l], nullptr, nullptr, h16, 128, N, NF);
        readout_kernel<<<((size_t)N * 128 + 255) / 256, 256, 0, stream>>>(
            h16, batch, rbuf + (size_t)l * G * NF, (unsigned*)(rbuf + (size_t)(3 + l) * G * NF), N);
    }

    head_kernel<<<G, 256, 0, stream>>>(rbuf, cnt, fc1w, fc1b, clsw, clsb, (float*)d_out, G);
    (void)h0; (void)ws_size;
}

// Round 4
// 1348.973 us; speedup vs baseline: 15.3070x; 1.0150x over previous
//
#include <hip/hip_runtime.h>
#include <cstdint>
#include <cstddef>

#define XF 10
#define NF 100
#define HF 200
#define BSHIFT 8

typedef _Float16 f16x8 __attribute__((ext_vector_type(8)));
typedef _Float16 h2 __attribute__((ext_vector_type(2)));
typedef float f32x4 __attribute__((ext_vector_type(4)));

static __device__ __forceinline__ float bn_scale(float g) {
    return g * 0.9999950000374997f; // 1/sqrt(1 + 1e-5)
}

// ---------------- CSR build ----------------
// counts[dst]++ and line-padded bucket counts (dst>>8, stride 16 to kill line contention)
__global__ __launch_bounds__(256) void hist2_kernel(const int* __restrict__ eidx,
                                                    int* __restrict__ counts,
                                                    int* __restrict__ bcount, int E) {
    int e = blockIdx.x * 256 + threadIdx.x;
    if (e >= E) return;
    int d = eidx[E + e];
    atomicAdd(&counts[d], 1);
    atomicAdd(&bcount[(d >> BSHIFT) * 16], 1);
}

__global__ __launch_bounds__(256) void scan1_kernel(const int* __restrict__ counts,
                                                    int* __restrict__ incl,
                                                    int* __restrict__ blocksum, int n) {
    __shared__ int s[256];
    int t = threadIdx.x;
    int base = blockIdx.x * 1024 + t * 4;
    int v0 = (base + 0 < n) ? counts[base + 0] : 0;
    int v1 = (base + 1 < n) ? counts[base + 1] : 0;
    int v2 = (base + 2 < n) ? counts[base + 2] : 0;
    int v3 = (base + 3 < n) ? counts[base + 3] : 0;
    int tot = v0 + v1 + v2 + v3;
    s[t] = tot;
    __syncthreads();
    for (int off = 1; off < 256; off <<= 1) {
        int add = (t >= off) ? s[t - off] : 0;
        __syncthreads();
        s[t] += add;
        __syncthreads();
    }
    int run = s[t] - tot;
    run += v0; if (base + 0 < n) incl[base + 0] = run;
    run += v1; if (base + 1 < n) incl[base + 1] = run;
    run += v2; if (base + 2 < n) incl[base + 2] = run;
    run += v3; if (base + 3 < n) incl[base + 3] = run;
    if (t == 255) blocksum[blockIdx.x] = s[255];
}

__global__ void scan2_kernel(int* __restrict__ blocksum, int nb) {
    if (blockIdx.x == 0 && threadIdx.x == 0) {
        int r = 0;
        for (int i = 0; i < nb; ++i) { int t = blocksum[i]; blocksum[i] = r; r += t; }
    }
}

__global__ __launch_bounds__(256) void scan3_kernel(const int* __restrict__ incl,
                                                    const int* __restrict__ blockoff,
                                                    int* __restrict__ indptr,
                                                    int* __restrict__ fillpos, int n) {
    int i = blockIdx.x * 256 + threadIdx.x;
    if (i >= n) return;
    int v = incl[i] + blockoff[i >> 10];
    indptr[i + 1] = v;
    fillpos[i + 1] = v;
    if (i == 0) { indptr[0] = 0; fillpos[0] = 0; }
}

// generic single-block exclusive scan for n<=1024 (strided input for padded counters)
__global__ void small_scan_kernel(const int* __restrict__ in, int in_stride,
                                  int* __restrict__ cur, int cur_stride,
                                  int* __restrict__ indptr, int n) {
    __shared__ int s[256];
    int t = threadIdx.x;
    int base = t * 4;
    int v[4]; int tot = 0;
#pragma unroll
    for (int i = 0; i < 4; ++i) {
        v[i] = (base + i < n) ? in[(base + i) * in_stride] : 0;
        tot += v[i];
    }
    s[t] = tot;
    __syncthreads();
    for (int off = 1; off < 256; off <<= 1) {
        int add = (t >= off) ? s[t - off] : 0;
        __syncthreads();
        s[t] += add;
        __syncthreads();
    }
    int run = s[t] - tot;
#pragma unroll
    for (int i = 0; i < 4; ++i) {
        if (base + i < n) {
            cur[(base + i) * cur_stride] = run;
            run += v[i];
            if (indptr) indptr[base + i + 1] = run;
        }
    }
    if (t == 0 && indptr) indptr[0] = 0;
}

// pass A: bucket edges by dst>>8 into (src,dst) pairs — ~391 sequential write streams
__global__ __launch_bounds__(256) void bucket_kernel(const int* __restrict__ eidx,
                                                     int* __restrict__ bcur,
                                                     int2* __restrict__ pairs, int E) {
    int e = blockIdx.x * 256 + threadIdx.x;
    if (e >= E) return;
    int s = eidx[e];
    int d = eidx[E + e];
    int p = atomicAdd(&bcur[(d >> BSHIFT) * 16], 1);
    pairs[p] = make_int2(s, d);
}

// pass B: fill esrc from bucket-ordered pairs — writes land in narrow dst-windows
__global__ __launch_bounds__(256) void fill2_kernel(const int2* __restrict__ pairs,
                                                    int* __restrict__ fillpos,
                                                    int* __restrict__ esrc, int E) {
    int e = blockIdx.x * 256 + threadIdx.x;
    if (e >= E) return;
    int2 pr = pairs[e];
    int p = atomicAdd(&fillpos[pr.y], 1);
    esrc[p] = pr.x;
}

// batch-CSR: per-graph node lists
__global__ __launch_bounds__(256) void gcnt_kernel(const int* __restrict__ batch,
                                                   int* __restrict__ gcount, int n) {
    int i = blockIdx.x * 256 + threadIdx.x;
    if (i < n) atomicAdd(&gcount[batch[i]], 1);
}

__global__ __launch_bounds__(256) void gfill_kernel(const int* __restrict__ batch,
                                                    int* __restrict__ gcur,
                                                    int* __restrict__ gnodes, int n) {
    int i = blockIdx.x * 256 + threadIdx.x;
    if (i >= n) return;
    int g = batch[i];
    int p = atomicAdd(&gcur[g], 1);
    gnodes[p] = i;
}

// ---------------- weight conversion to fp16, K padded ----------------
struct WArgs {
    const float* src[6];
    _Float16* dst[6];
};
__global__ __launch_bounds__(256) void wconv_kernel(WArgs wa) {
    int w = blockIdx.y;
    int idx = blockIdx.x * 256 + threadIdx.x; // < 32768
    int J, K, j, k;
    if (w < 3) { J = 200; K = 100; j = idx >> 7; k = idx & 127; }
    else       { J = 100; K = 200; j = idx >> 8; k = idx & 255; }
    float v = (j < J && k < K) ? wa.src[w][j * K + k] : 0.f;
    wa.dst[w][idx] = (_Float16)v;
}

// ---------------- layer-1 input linear (10 -> 100) -> fp16, stride 128 ---------
__global__ __launch_bounds__(256) void lin10_kernel(const float* __restrict__ x,
                                                    const float* __restrict__ sw,
                                                    const float* __restrict__ sb,
                                                    const float* __restrict__ dw,
                                                    const float* __restrict__ db,
                                                    _Float16* __restrict__ h16,
                                                    _Float16* __restrict__ xd16, int n_nodes) {
    int idx = blockIdx.x * 256 + threadIdx.x;
    if (idx >= n_nodes * 64) return;
    int n = idx >> 6, f2 = idx & 63;
    float a0 = 0.f, a1 = 0.f, b0 = 0.f, b1 = 0.f;
    if (f2 < 50) {
        int f0 = 2 * f2, f1 = 2 * f2 + 1;
        float xv[XF];
#pragma unroll
        for (int k = 0; k < XF; ++k) xv[k] = x[n * XF + k];
        a0 = sb[f0]; a1 = sb[f1]; b0 = db[f0]; b1 = db[f1];
#pragma unroll
        for (int k = 0; k < XF; ++k) {
            a0 += xv[k] * sw[f0 * XF + k];
            a1 += xv[k] * sw[f1 * XF + k];
            b0 += xv[k] * dw[f0 * XF + k];
            b1 += xv[k] * dw[f1 * XF + k];
        }
    }
    ((h2*)(h16 + (size_t)n * 128))[f2] = (h2){(_Float16)a0, (_Float16)a1};
    ((h2*)(xd16 + (size_t)n * 128))[f2] = (h2){(_Float16)b0, (_Float16)b1};
}

// ---------------- softmax aggregation: 1 wave per node, online softmax --------
__global__ __launch_bounds__(128) void agg_kernel(const _Float16* __restrict__ h16,
                                                  const _Float16* __restrict__ xd16,
                                                  const int* __restrict__ indptr,
                                                  const int* __restrict__ esrc,
                                                  _Float16* __restrict__ c16, int n_nodes) {
    int n = blockIdx.x * 2 + (threadIdx.x >> 6);
    if (n >= n_nodes) return;
    int lane = threadIdx.x & 63;
    int beg = __builtin_amdgcn_readfirstlane(indptr[n]);
    int end = __builtin_amdgcn_readfirstlane(indptr[n + 1]);
    const h2* hb = (const h2*)h16;
    float m0 = 0.f, m1 = 0.f, d0 = 0.f, d1 = 0.f, s0 = 0.f, s1 = 0.f;
    h2 cur = (h2){(_Float16)0.f, (_Float16)0.f};
    if (beg < end) {
        int s = esrc[beg];
        cur = hb[(size_t)s * 64 + lane];
    }
    for (int j = beg; j < end; ++j) {
        h2 nxt = cur;
        if (j + 1 < end) {
            int s2 = esrc[j + 1];
            nxt = hb[(size_t)s2 * 64 + lane];
        }
        float v0 = (float)cur.x, v1 = (float)cur.y;
        float a0 = fmaxf(v0, 0.f) + 1e-7f;
        float a1 = fmaxf(v1, 0.f) + 1e-7f;
        float nm0 = fmaxf(m0, a0), nm1 = fmaxf(m1, a1);
        float sc0 = __expf(m0 - nm0), e0 = __expf(a0 - nm0);
        float sc1 = __expf(m1 - nm1), e1 = __expf(a1 - nm1);
        d0 = d0 * sc0 + e0; s0 = s0 * sc0 + e0 * a0; m0 = nm0;
        d1 = d1 * sc1 + e1; s1 = s1 * sc1 + e1 * a1; m1 = nm1;
        cur = nxt;
    }
    float g0 = s0 / (d0 + 1e-16f);
    float g1 = s1 / (d1 + 1e-16f);
    float o0 = 0.f, o1 = 0.f;
    if (lane < 50) {
        h2 xv = ((const h2*)(xd16 + (size_t)n * 128))[lane];
        o0 = g0 + (float)xv.x;
        o1 = g1 + (float)xv.y;
    }
    ((h2*)(c16 + (size_t)n * 128))[lane] = (h2){(_Float16)o0, (_Float16)o1};
}

// ---------------- MFMA f16 GEMM: out16 = relu(opt-BN(A @ W^T + bias)) ---------
template <int KSTEPS, int LDA, bool BN>
__global__ __launch_bounds__(256, 4) void mfma_gemm_kernel(const _Float16* __restrict__ A,
                                                           const _Float16* __restrict__ W,
                                                           const float* __restrict__ bias,
                                                           const float* __restrict__ gamma,
                                                           const float* __restrict__ beta,
                                                           _Float16* __restrict__ out16,
                                                           int ldo, int M, int J) {
    int wave = threadIdx.x >> 6;
    int lane = threadIdx.x & 63;
    int l15 = lane & 15, quad = lane >> 4;
    long m0 = (long)blockIdx.x * 64;
    int j0 = blockIdx.y * 64 + wave * 16;
    const _Float16* aptr = A + (m0 + l15) * LDA + quad * 8;
    const _Float16* wptr = W + (size_t)(j0 + l15) * LDA + quad * 8;
    f32x4 acc0 = {0.f, 0.f, 0.f, 0.f}, acc1 = acc0, acc2 = acc0, acc3 = acc0;
#pragma unroll 2
    for (int ks = 0; ks < KSTEPS; ++ks) {
        f16x8 b  = *(const f16x8*)(wptr + ks * 32);
        f16x8 a0 = *(const f16x8*)(aptr + ks * 32);
        f16x8 a1 = *(const f16x8*)(aptr + 16 * LDA + ks * 32);
        f16x8 a2 = *(const f16x8*)(aptr + 32 * LDA + ks * 32);
        f16x8 a3 = *(const f16x8*)(aptr + 48 * LDA + ks * 32);
        acc0 = __builtin_amdgcn_mfma_f32_16x16x32_f16(a0, b, acc0, 0, 0, 0);
        acc1 = __builtin_amdgcn_mfma_f32_16x16x32_f16(a1, b, acc1, 0, 0, 0);
        acc2 = __builtin_amdgcn_mfma_f32_16x16x32_f16(a2, b, acc2, 0, 0, 0);
        acc3 = __builtin_amdgcn_mfma_f32_16x16x32_f16(a3, b, acc3, 0, 0, 0);
    }
    int col = j0 + l15;
    bool cv = col < J;
    float bi = cv ? bias[col] : 0.f;
    float gm = 1.f, bt = 0.f;
    if (BN && cv) { gm = bn_scale(gamma[col]); bt = beta[col]; }
    f32x4 accs[4] = {acc0, acc1, acc2, acc3};
#pragma unroll
    for (int i = 0; i < 4; ++i) {
#pragma unroll
        for (int r = 0; r < 4; ++r) {
            long row = m0 + i * 16 + quad * 4 + r;
            float v = accs[i][r] + bi;
            if (BN) v = v * gm + bt;
            v = fmaxf(v, 0.f);
            if (!cv) v = 0.f;
            if (row < M) out16[row * ldo + col] = (_Float16)v;
        }
    }
}

// ---------------- readout: per-graph gather (no atomics) ----------------
// one block (4 waves) per graph; lane handles 2 features; LDS combine
__global__ __launch_bounds__(256) void readout2_kernel(const _Float16* __restrict__ h16,
                                                       const int* __restrict__ gindptr,
                                                       const int* __restrict__ gnodes,
                                                       float* __restrict__ sum,
                                                       float* __restrict__ mx) {
    __shared__ float ls[4][128];
    __shared__ float lm[4][128];
    int g = blockIdx.x;
    int wave = threadIdx.x >> 6;
    int lane = threadIdx.x & 63;
    int beg = gindptr[g], end = gindptr[g + 1];
    const h2* hb = (const h2*)h16;
    float s0 = 0.f, s1 = 0.f, m0 = 0.f, m1 = 0.f;
    int i = beg + wave;
    int nd = (i < end) ? gnodes[i] : 0;
    for (; i < end; i += 4) {
        int ndn = (i + 4 < end) ? gnodes[i + 4] : 0;
        h2 v = hb[(size_t)nd * 64 + lane];
        float v0 = (float)v.x, v1 = (float)v.y;
        s0 += v0; s1 += v1;
        m0 = fmaxf(m0, v0); m1 = fmaxf(m1, v1);
        nd = ndn;
    }
    ls[wave][2 * lane] = s0; ls[wave][2 * lane + 1] = s1;
    lm[wave][2 * lane] = m0; lm[wave][2 * lane + 1] = m1;
    __syncthreads();
    int f = threadIdx.x;
    if (f < NF) {
        float ss = ls[0][f] + ls[1][f] + ls[2][f] + ls[3][f];
        float mm = fmaxf(fmaxf(lm[0][f], lm[1][f]), fmaxf(lm[2][f], lm[3][f]));
        sum[(size_t)g * NF + f] = ss;
        mx[(size_t)g * NF + f] = mm;
    }
}

// ---------------- head: encode + fc1 + classifier ----------------
__global__ __launch_bounds__(256) void head_kernel(const float* __restrict__ rbuf,
                                                   const int* __restrict__ gindptr,
                                                   const float* __restrict__ fc1w,
                                                   const float* __restrict__ fc1b,
                                                   const float* __restrict__ clsw,
                                                   const float* __restrict__ clsb,
                                                   float* __restrict__ out, int G) {
    __shared__ float enc[HF];
    __shared__ float z[NF];
    int g = blockIdx.x;
    int t = threadIdx.x;
    const float* sum1 = rbuf;
    const float* sum2 = rbuf + (size_t)G * NF;
    const float* sum3 = rbuf + (size_t)2 * G * NF;
    const float* mx1 = rbuf + (size_t)3 * G * NF;
    const float* mx2 = rbuf + (size_t)4 * G * NF;
    const float* mx3 = rbuf + (size_t)5 * G * NF;
    float ic = 1.f / fmaxf((float)(gindptr[g + 1] - gindptr[g]), 1.f);
    if (t < HF) {
        float e;
        if (t < NF) {
            e = fmaxf(sum1[g * NF + t] * ic, 0.f) + fmaxf(sum2[g * NF + t] * ic, 0.f) +
                fmaxf(sum3[g * NF + t] * ic, 0.f);
        } else {
            int f = t - NF;
            e = fmaxf(mx1[g * NF + f], 0.f) + fmaxf(mx2[g * NF + f], 0.f) +
                fmaxf(mx3[g * NF + f], 0.f);
        }
        enc[t] = e;
        out[G * 2 + (size_t)g * HF + t] = e;
    }
    __syncthreads();
    if (t < NF) {
        float a = fc1b[t];
        for (int k = 0; k < HF; ++k) a += enc[k] * fc1w[t * HF + k];
        z[t] = fmaxf(a, 0.f);
    }
    __syncthreads();
    if (t < 2) {
        float a = clsb[t];
        for (int k = 0; k < NF; ++k) a += z[k] * clsw[t * NF + k];
        out[(size_t)g * 2 + t] = a;
    }
}

extern "C" void kernel_launch(void* const* d_in, const int* in_sizes, int n_in,
                              void* d_out, int out_size, void* d_ws, size_t ws_size,
                              hipStream_t stream) {
    const float* x        = (const float*)d_in[0];
    const int*   eidx     = (const int*)d_in[1];
    const int*   batch    = (const int*)d_in[2];
    const float* c1_src_w = (const float*)d_in[3];
    const float* c1_src_b = (const float*)d_in[4];
    const float* c1_dst_w = (const float*)d_in[5];
    const float* c1_dst_b = (const float*)d_in[6];
    const float* cw1[3] = {(const float*)d_in[7],  (const float*)d_in[13], (const float*)d_in[19]};
    const float* cb1[3] = {(const float*)d_in[8],  (const float*)d_in[14], (const float*)d_in[20]};
    const float* cg[3]  = {(const float*)d_in[9],  (const float*)d_in[15], (const float*)d_in[21]};
    const float* cbe[3] = {(const float*)d_in[10], (const float*)d_in[16], (const float*)d_in[22]};
    const float* cw2[3] = {(const float*)d_in[11], (const float*)d_in[17], (const float*)d_in[23]};
    const float* cb2[3] = {(const float*)d_in[12], (const float*)d_in[18], (const float*)d_in[24]};
    const float* fc1w = (const float*)d_in[25];
    const float* fc1b = (const float*)d_in[26];
    const float* clsw = (const float*)d_in[27];
    const float* clsb = (const float*)d_in[28];

    const int N = in_sizes[0] / XF;
    const int E = in_sizes[1] / 2;
    const int G = out_size / 202;
    const int NB = (N + 1023) / 1024;
    const int Mpad = (N + 63) & ~63;
    const int NBK = (N + 255) >> BSHIFT; // dst buckets

    char* p = (char*)d_ws;
    auto alloc = [&](size_t bytes) {
        char* r = p;
        p += (bytes + 255) & ~(size_t)255;
        return r;
    };
    _Float16* h16  = (_Float16*)alloc((size_t)Mpad * 128 * 2);
    _Float16* C16  = (_Float16*)alloc((size_t)Mpad * 128 * 2);
    _Float16* HH16 = (_Float16*)alloc((size_t)Mpad * 256 * 2);
    _Float16* xd16 = HH16; // alias: xd16 dead before gemm1 writes HH16
    _Float16* W16  = (_Float16*)alloc((size_t)6 * 32768 * 2);
    int2* pairs   = (int2*)alloc((size_t)E * 8);
    int* esrc     = (int*)alloc((size_t)E * 4);
    int* indptr   = (int*)alloc((size_t)(N + 1) * 4);
    int* fillpos  = (int*)alloc((size_t)(N + 1) * 4);
    int* incl     = (int*)alloc((size_t)N * 4);
    int* blocksum = (int*)alloc((size_t)NB * 4);
    // zeroed block: counts[N] | bcount[NBK*16] | gcount[G]
    int* zblock   = (int*)alloc(((size_t)N + (size_t)NBK * 16 + G) * 4);
    int* counts = zblock;
    int* bcount = zblock + N;
    int* gcount = zblock + N + (size_t)NBK * 16;
    int* bcur     = (int*)alloc((size_t)NBK * 16 * 4);
    int* gcur     = (int*)alloc((size_t)G * 4);
    int* gindptr  = (int*)alloc((size_t)(G + 1) * 4);
    int* gnodes   = (int*)alloc((size_t)N * 4);
    float* rbuf   = (float*)alloc((size_t)6 * G * NF * 4);

    hipMemsetAsync(zblock, 0, ((size_t)N + (size_t)NBK * 16 + G) * 4, stream);

    // node-CSR counts + bucket counts
    hist2_kernel<<<(E + 255) / 256, 256, 0, stream>>>(eidx, counts, bcount, E);
    scan1_kernel<<<NB, 256, 0, stream>>>(counts, incl, blocksum, N);
    scan2_kernel<<<1, 64, 0, stream>>>(blocksum, NB);
    scan3_kernel<<<(N + 255) / 256, 256, 0, stream>>>(incl, blocksum, indptr, fillpos, N);
    // bucket scan -> bcur; pass A bucket scatter; pass B localized fill
    small_scan_kernel<<<1, 256, 0, stream>>>(bcount, 16, bcur, 16, nullptr, NBK);
    bucket_kernel<<<(E + 255) / 256, 256, 0, stream>>>(eidx, bcur, pairs, E);
    fill2_kernel<<<(E + 255) / 256, 256, 0, stream>>>(pairs, fillpos, esrc, E);
    // batch-CSR for readout
    gcnt_kernel<<<(N + 255) / 256, 256, 0, stream>>>(batch, gcount, N);
    small_scan_kernel<<<1, 256, 0, stream>>>(gcount, 1, gcur, 1, gindptr, G);
    gfill_kernel<<<(N + 255) / 256, 256, 0, stream>>>(batch, gcur, gnodes, N);

    // weights -> fp16 (padded)
    WArgs wa;
    for (int l = 0; l < 3; ++l) {
        wa.src[l] = cw1[l];     wa.dst[l] = W16 + (size_t)l * 32768;
        wa.src[3 + l] = cw2[l]; wa.dst[3 + l] = W16 + (size_t)(3 + l) * 32768;
    }
    wconv_kernel<<<dim3(128, 6), 256, 0, stream>>>(wa);

    // layer-1 input transforms
    lin10_kernel<<<((size_t)N * 64 + 255) / 256, 256, 0, stream>>>(x, c1_src_w, c1_src_b,
                                                                   c1_dst_w, c1_dst_b, h16, xd16, N);

    for (int l = 0; l < 3; ++l) {
        const _Float16* xdp = (l == 0) ? xd16 : h16;
        agg_kernel<<<(N + 1) / 2, 128, 0, stream>>>(h16, xdp, indptr, esrc, C16, N);
        mfma_gemm_kernel<4, 128, true><<<dim3(Mpad / 64, 4), 256, 0, stream>>>(
            C16, W16 + (size_t)l * 32768, cb1[l], cg[l], cbe[l], HH16, 256, N, HF);
        mfma_gemm_kernel<8, 256, false><<<dim3(Mpad / 64, 2), 256, 0, stream>>>(
            HH16, W16 + (size_t)(3 + l) * 32768, cb2[l], nullptr, nullptr, h16, 128, N, NF);
        readout2_kernel<<<G, 256, 0, stream>>>(h16, gindptr, gnodes,
                                               rbuf + (size_t)l * G * NF,
                                               rbuf + (size_t)(3 + l) * G * NF);
    }

    head_kernel<<<G, 256, 0, stream>>>(rbuf, gindptr, fc1w, fc1b, clsw, clsb, (float*)d_out, G);
    (void)ws_size;
}

// Round 5
// 1130.707 us; speedup vs baseline: 18.2618x; 1.1930x over previous
//
#include <hip/hip_runtime.h>
#include <cstdint>
#include <cstddef>

#define XF 10
#define NF 100
#define HF 200
#define BSHIFT 8
#define NBLK_G 512   // blocks for count/scatter passes
#define MAXBK 512    // max dst buckets (N <= 131072)

typedef _Float16 f16x8 __attribute__((ext_vector_type(8)));
typedef _Float16 h2 __attribute__((ext_vector_type(2)));
typedef float f32x4 __attribute__((ext_vector_type(4)));

static __device__ __forceinline__ float bn_scale(float g) {
    return g * 0.9999950000374997f; // 1/sqrt(1 + 1e-5)
}

// ---------------- CSR build: radix partition by dst, no global data atomics ----
// pass 1: per-block LDS histogram of dst buckets -> bmat[bucket][block]
__global__ __launch_bounds__(256) void csr_count_kernel(const int* __restrict__ eidx,
                                                        int* __restrict__ bmat,
                                                        int E, int nbk, int epb) {
    __shared__ int hist[MAXBK];
    for (int j = threadIdx.x; j < nbk; j += 256) hist[j] = 0;
    __syncthreads();
    int base = blockIdx.x * epb;
    int end = base + epb; if (end > E) end = E;
    for (int e = base + threadIdx.x; e < end; e += 256) {
        int d = eidx[E + e];
        atomicAdd(&hist[d >> BSHIFT], 1);
    }
    __syncthreads();
    for (int j = threadIdx.x; j < nbk; j += 256)
        bmat[(size_t)j * NBLK_G + blockIdx.x] = hist[j];
}

// chunked exclusive scan of bmat (in place), 1024 elems/block
__global__ __launch_bounds__(256) void scan1x_kernel(int* __restrict__ a,
                                                     int* __restrict__ blocksum, int n) {
    __shared__ int s[256];
    int t = threadIdx.x;
    int base = blockIdx.x * 1024 + t * 4;
    int v[4]; int tot = 0;
#pragma unroll
    for (int i = 0; i < 4; ++i) {
        v[i] = (base + i < n) ? a[base + i] : 0;
        tot += v[i];
    }
    s[t] = tot;
    __syncthreads();
    for (int off = 1; off < 256; off <<= 1) {
        int add = (t >= off) ? s[t - off] : 0;
        __syncthreads();
        s[t] += add;
        __syncthreads();
    }
    int run = s[t] - tot; // exclusive within chunk
#pragma unroll
    for (int i = 0; i < 4; ++i) {
        if (base + i < n) a[base + i] = run;
        run += v[i];
    }
    if (t == 255) blocksum[blockIdx.x] = s[255];
}

__global__ void scan2_kernel(int* __restrict__ blocksum, int nb) {
    if (blockIdx.x == 0 && threadIdx.x == 0) {
        int r = 0;
        for (int i = 0; i < nb; ++i) { int t = blocksum[i]; blocksum[i] = r; r += t; }
    }
}

__global__ __launch_bounds__(256) void scan3x_kernel(int* __restrict__ a,
                                                     const int* __restrict__ blockoff, int n) {
    int i = blockIdx.x * 256 + threadIdx.x;
    if (i < n) a[i] += blockoff[i >> 10];
}

// pass 3: scatter packed (src | dlocal<<24) at deterministic positions via LDS cursors
__global__ __launch_bounds__(256) void csr_scatter_kernel(const int* __restrict__ eidx,
                                                          const int* __restrict__ bmat,
                                                          int* __restrict__ packed,
                                                          int E, int nbk, int epb) {
    __shared__ int cur[MAXBK];
    for (int j = threadIdx.x; j < nbk; j += 256)
        cur[j] = bmat[(size_t)j * NBLK_G + blockIdx.x];
    __syncthreads();
    int base = blockIdx.x * epb;
    int end = base + epb; if (end > E) end = E;
    for (int e = base + threadIdx.x; e < end; e += 256) {
        int s = eidx[e];
        int d = eidx[E + e];
        int p = atomicAdd(&cur[d >> BSHIFT], 1);
        packed[p] = s | ((d & 255) << 24);
    }
}

// pass 4: one block per bucket -> indptr + esrc (LDS count/scan/cursors only)
__global__ __launch_bounds__(256) void csr_finalize_kernel(const int* __restrict__ bmat,
                                                           const int* __restrict__ packed,
                                                           int* __restrict__ indptr,
                                                           int* __restrict__ esrc,
                                                           int E, int nbk, int n) {
    __shared__ int cnt[256];
    __shared__ int s[256];
    __shared__ int cur[256];
    int b = blockIdx.x;
    int t = threadIdx.x;
    int ebeg = bmat[(size_t)b * NBLK_G];
    int eend = (b + 1 < nbk) ? bmat[(size_t)(b + 1) * NBLK_G] : E;
    cnt[t] = 0;
    __syncthreads();
    for (int i = ebeg + t; i < eend; i += 256)
        atomicAdd(&cnt[((unsigned)packed[i]) >> 24], 1);
    __syncthreads();
    int tot = cnt[t];
    s[t] = tot;
    __syncthreads();
    for (int off = 1; off < 256; off <<= 1) {
        int add = (t >= off) ? s[t - off] : 0;
        __syncthreads();
        s[t] += add;
        __syncthreads();
    }
    int off_ex = s[t] - tot; // exclusive
    int node = (b << BSHIFT) + t;
    if (node < n) indptr[node] = ebeg + off_ex;
    if (b == nbk - 1 && t == 0) indptr[n] = E;
    cur[t] = ebeg + off_ex;
    __syncthreads();
    for (int i = ebeg + t; i < eend; i += 256) {
        int p = packed[i];
        int pos = atomicAdd(&cur[((unsigned)p) >> 24], 1);
        esrc[pos] = p & 0xFFFFFF;
    }
}

// batch-CSR: per-graph node lists
__global__ __launch_bounds__(256) void gcnt_kernel(const int* __restrict__ batch,
                                                   int* __restrict__ gcount, int n) {
    int i = blockIdx.x * 256 + threadIdx.x;
    if (i < n) atomicAdd(&gcount[batch[i]], 1);
}

__global__ void small_scan_kernel(const int* __restrict__ in, int in_stride,
                                  int* __restrict__ cur, int cur_stride,
                                  int* __restrict__ indptr, int n) {
    __shared__ int s[256];
    int t = threadIdx.x;
    int base = t * 4;
    int v[4]; int tot = 0;
#pragma unroll
    for (int i = 0; i < 4; ++i) {
        v[i] = (base + i < n) ? in[(base + i) * in_stride] : 0;
        tot += v[i];
    }
    s[t] = tot;
    __syncthreads();
    for (int off = 1; off < 256; off <<= 1) {
        int add = (t >= off) ? s[t - off] : 0;
        __syncthreads();
        s[t] += add;
        __syncthreads();
    }
    int run = s[t] - tot;
#pragma unroll
    for (int i = 0; i < 4; ++i) {
        if (base + i < n) {
            cur[(base + i) * cur_stride] = run;
            run += v[i];
            if (indptr) indptr[base + i + 1] = run;
        }
    }
    if (t == 0 && indptr) indptr[0] = 0;
}

__global__ __launch_bounds__(256) void gfill_kernel(const int* __restrict__ batch,
                                                    int* __restrict__ gcur,
                                                    int* __restrict__ gnodes, int n) {
    int i = blockIdx.x * 256 + threadIdx.x;
    if (i >= n) return;
    int g = batch[i];
    int p = atomicAdd(&gcur[g], 1);
    gnodes[p] = i;
}

// ---------------- weight conversion to fp16, K padded ----------------
struct WArgs {
    const float* src[6];
    _Float16* dst[6];
};
__global__ __launch_bounds__(256) void wconv_kernel(WArgs wa) {
    int w = blockIdx.y;
    int idx = blockIdx.x * 256 + threadIdx.x; // < 32768
    int J, K, j, k;
    if (w < 3) { J = 200; K = 100; j = idx >> 7; k = idx & 127; }
    else       { J = 100; K = 200; j = idx >> 8; k = idx & 255; }
    float v = (j < J && k < K) ? wa.src[w][j * K + k] : 0.f;
    wa.dst[w][idx] = (_Float16)v;
}

// ---------------- layer-1 input linear (10 -> 100) -> fp16, stride 128 ---------
__global__ __launch_bounds__(256) void lin10_kernel(const float* __restrict__ x,
                                                    const float* __restrict__ sw,
                                                    const float* __restrict__ sb,
                                                    const float* __restrict__ dw,
                                                    const float* __restrict__ db,
                                                    _Float16* __restrict__ h16,
                                                    _Float16* __restrict__ xd16, int n_nodes) {
    int idx = blockIdx.x * 256 + threadIdx.x;
    if (idx >= n_nodes * 64) return;
    int n = idx >> 6, f2 = idx & 63;
    float a0 = 0.f, a1 = 0.f, b0 = 0.f, b1 = 0.f;
    if (f2 < 50) {
        int f0 = 2 * f2, f1 = 2 * f2 + 1;
        float xv[XF];
#pragma unroll
        for (int k = 0; k < XF; ++k) xv[k] = x[n * XF + k];
        a0 = sb[f0]; a1 = sb[f1]; b0 = db[f0]; b1 = db[f1];
#pragma unroll
        for (int k = 0; k < XF; ++k) {
            a0 += xv[k] * sw[f0 * XF + k];
            a1 += xv[k] * sw[f1 * XF + k];
            b0 += xv[k] * dw[f0 * XF + k];
            b1 += xv[k] * dw[f1 * XF + k];
        }
    }
    ((h2*)(h16 + (size_t)n * 128))[f2] = (h2){(_Float16)a0, (_Float16)a1};
    ((h2*)(xd16 + (size_t)n * 128))[f2] = (h2){(_Float16)b0, (_Float16)b1};
}

// ---------------- softmax aggregation: 1 wave per node, online softmax --------
__global__ __launch_bounds__(128) void agg_kernel(const _Float16* __restrict__ h16,
                                                  const _Float16* __restrict__ xd16,
                                                  const int* __restrict__ indptr,
                                                  const int* __restrict__ esrc,
                                                  _Float16* __restrict__ c16, int n_nodes) {
    int n = blockIdx.x * 2 + (threadIdx.x >> 6);
    if (n >= n_nodes) return;
    int lane = threadIdx.x & 63;
    int beg = __builtin_amdgcn_readfirstlane(indptr[n]);
    int end = __builtin_amdgcn_readfirstlane(indptr[n + 1]);
    const h2* hb = (const h2*)h16;
    float m0 = 0.f, m1 = 0.f, d0 = 0.f, d1 = 0.f, s0 = 0.f, s1 = 0.f;
    h2 cur = (h2){(_Float16)0.f, (_Float16)0.f};
    if (beg < end) {
        int s = esrc[beg];
        cur = hb[(size_t)s * 64 + lane];
    }
    for (int j = beg; j < end; ++j) {
        h2 nxt = cur;
        if (j + 1 < end) {
            int s2 = esrc[j + 1];
            nxt = hb[(size_t)s2 * 64 + lane];
        }
        float v0 = (float)cur.x, v1 = (float)cur.y;
        float a0 = fmaxf(v0, 0.f) + 1e-7f;
        float a1 = fmaxf(v1, 0.f) + 1e-7f;
        float nm0 = fmaxf(m0, a0), nm1 = fmaxf(m1, a1);
        float sc0 = __expf(m0 - nm0), e0 = __expf(a0 - nm0);
        float sc1 = __expf(m1 - nm1), e1 = __expf(a1 - nm1);
        d0 = d0 * sc0 + e0; s0 = s0 * sc0 + e0 * a0; m0 = nm0;
        d1 = d1 * sc1 + e1; s1 = s1 * sc1 + e1 * a1; m1 = nm1;
        cur = nxt;
    }
    float g0 = s0 / (d0 + 1e-16f);
    float g1 = s1 / (d1 + 1e-16f);
    float o0 = 0.f, o1 = 0.f;
    if (lane < 50) {
        h2 xv = ((const h2*)(xd16 + (size_t)n * 128))[lane];
        o0 = g0 + (float)xv.x;
        o1 = g1 + (float)xv.y;
    }
    ((h2*)(c16 + (size_t)n * 128))[lane] = (h2){(_Float16)o0, (_Float16)o1};
}

// ---------------- MFMA f16 GEMM: out16 = relu(opt-BN(A @ W^T + bias)) ---------
template <int KSTEPS, int LDA, bool BN>
__global__ __launch_bounds__(256, 4) void mfma_gemm_kernel(const _Float16* __restrict__ A,
                                                           const _Float16* __restrict__ W,
                                                           const float* __restrict__ bias,
                                                           const float* __restrict__ gamma,
                                                           const float* __restrict__ beta,
                                                           _Float16* __restrict__ out16,
                                                           int ldo, int M, int J) {
    int wave = threadIdx.x >> 6;
    int lane = threadIdx.x & 63;
    int l15 = lane & 15, quad = lane >> 4;
    long m0 = (long)blockIdx.x * 64;
    int j0 = blockIdx.y * 64 + wave * 16;
    const _Float16* aptr = A + (m0 + l15) * LDA + quad * 8;
    const _Float16* wptr = W + (size_t)(j0 + l15) * LDA + quad * 8;
    f32x4 acc0 = {0.f, 0.f, 0.f, 0.f}, acc1 = acc0, acc2 = acc0, acc3 = acc0;
#pragma unroll 2
    for (int ks = 0; ks < KSTEPS; ++ks) {
        f16x8 b  = *(const f16x8*)(wptr + ks * 32);
        f16x8 a0 = *(const f16x8*)(aptr + ks * 32);
        f16x8 a1 = *(const f16x8*)(aptr + 16 * LDA + ks * 32);
        f16x8 a2 = *(const f16x8*)(aptr + 32 * LDA + ks * 32);
        f16x8 a3 = *(const f16x8*)(aptr + 48 * LDA + ks * 32);
        acc0 = __builtin_amdgcn_mfma_f32_16x16x32_f16(a0, b, acc0, 0, 0, 0);
        acc1 = __builtin_amdgcn_mfma_f32_16x16x32_f16(a1, b, acc1, 0, 0, 0);
        acc2 = __builtin_amdgcn_mfma_f32_16x16x32_f16(a2, b, acc2, 0, 0, 0);
        acc3 = __builtin_amdgcn_mfma_f32_16x16x32_f16(a3, b, acc3, 0, 0, 0);
    }
    int col = j0 + l15;
    bool cv = col < J;
    float bi = cv ? bias[col] : 0.f;
    float gm = 1.f, bt = 0.f;
    if (BN && cv) { gm = bn_scale(gamma[col]); bt = beta[col]; }
    f32x4 accs[4] = {acc0, acc1, acc2, acc3};
#pragma unroll
    for (int i = 0; i < 4; ++i) {
#pragma unroll
        for (int r = 0; r < 4; ++r) {
            long row = m0 + i * 16 + quad * 4 + r;
            float v = accs[i][r] + bi;
            if (BN) v = v * gm + bt;
            v = fmaxf(v, 0.f);
            if (!cv) v = 0.f;
            if (row < M) out16[row * ldo + col] = (_Float16)v;
        }
    }
}

// ---------------- readout: per-graph gather (no atomics) ----------------
__global__ __launch_bounds__(256) void readout2_kernel(const _Float16* __restrict__ h16,
                                                       const int* __restrict__ gindptr,
                                                       const int* __restrict__ gnodes,
                                                       float* __restrict__ sum,
                                                       float* __restrict__ mx) {
    __shared__ float ls[4][128];
    __shared__ float lm[4][128];
    int g = blockIdx.x;
    int wave = threadIdx.x >> 6;
    int lane = threadIdx.x & 63;
    int beg = gindptr[g], end = gindptr[g + 1];
    const h2* hb = (const h2*)h16;
    float s0 = 0.f, s1 = 0.f, m0 = 0.f, m1 = 0.f;
    int i = beg + wave;
    int nd = (i < end) ? gnodes[i] : 0;
    for (; i < end; i += 4) {
        int ndn = (i + 4 < end) ? gnodes[i + 4] : 0;
        h2 v = hb[(size_t)nd * 64 + lane];
        float v0 = (float)v.x, v1 = (float)v.y;
        s0 += v0; s1 += v1;
        m0 = fmaxf(m0, v0); m1 = fmaxf(m1, v1);
        nd = ndn;
    }
    ls[wave][2 * lane] = s0; ls[wave][2 * lane + 1] = s1;
    lm[wave][2 * lane] = m0; lm[wave][2 * lane + 1] = m1;
    __syncthreads();
    int f = threadIdx.x;
    if (f < NF) {
        float ss = ls[0][f] + ls[1][f] + ls[2][f] + ls[3][f];
        float mm = fmaxf(fmaxf(lm[0][f], lm[1][f]), fmaxf(lm[2][f], lm[3][f]));
        sum[(size_t)g * NF + f] = ss;
        mx[(size_t)g * NF + f] = mm;
    }
}

// ---------------- head: encode + fc1 + classifier ----------------
__global__ __launch_bounds__(256) void head_kernel(const float* __restrict__ rbuf,
                                                   const int* __restrict__ gindptr,
                                                   const float* __restrict__ fc1w,
                                                   const float* __restrict__ fc1b,
                                                   const float* __restrict__ clsw,
                                                   const float* __restrict__ clsb,
                                                   float* __restrict__ out, int G) {
    __shared__ float enc[HF];
    __shared__ float z[NF];
    int g = blockIdx.x;
    int t = threadIdx.x;
    const float* sum1 = rbuf;
    const float* sum2 = rbuf + (size_t)G * NF;
    const float* sum3 = rbuf + (size_t)2 * G * NF;
    const float* mx1 = rbuf + (size_t)3 * G * NF;
    const float* mx2 = rbuf + (size_t)4 * G * NF;
    const float* mx3 = rbuf + (size_t)5 * G * NF;
    float ic = 1.f / fmaxf((float)(gindptr[g + 1] - gindptr[g]), 1.f);
    if (t < HF) {
        float e;
        if (t < NF) {
            e = fmaxf(sum1[g * NF + t] * ic, 0.f) + fmaxf(sum2[g * NF + t] * ic, 0.f) +
                fmaxf(sum3[g * NF + t] * ic, 0.f);
        } else {
            int f = t - NF;
            e = fmaxf(mx1[g * NF + f], 0.f) + fmaxf(mx2[g * NF + f], 0.f) +
                fmaxf(mx3[g * NF + f], 0.f);
        }
        enc[t] = e;
        out[G * 2 + (size_t)g * HF + t] = e;
    }
    __syncthreads();
    if (t < NF) {
        float a = fc1b[t];
        for (int k = 0; k < HF; ++k) a += enc[k] * fc1w[t * HF + k];
        z[t] = fmaxf(a, 0.f);
    }
    __syncthreads();
    if (t < 2) {
        float a = clsb[t];
        for (int k = 0; k < NF; ++k) a += z[k] * clsw[t * NF + k];
        out[(size_t)g * 2 + t] = a;
    }
}

extern "C" void kernel_launch(void* const* d_in, const int* in_sizes, int n_in,
                              void* d_out, int out_size, void* d_ws, size_t ws_size,
                              hipStream_t stream) {
    const float* x        = (const float*)d_in[0];
    const int*   eidx     = (const int*)d_in[1];
    const int*   batch    = (const int*)d_in[2];
    const float* c1_src_w = (const float*)d_in[3];
    const float* c1_src_b = (const float*)d_in[4];
    const float* c1_dst_w = (const float*)d_in[5];
    const float* c1_dst_b = (const float*)d_in[6];
    const float* cw1[3] = {(const float*)d_in[7],  (const float*)d_in[13], (const float*)d_in[19]};
    const float* cb1[3] = {(const float*)d_in[8],  (const float*)d_in[14], (const float*)d_in[20]};
    const float* cg[3]  = {(const float*)d_in[9],  (const float*)d_in[15], (const float*)d_in[21]};
    const float* cbe[3] = {(const float*)d_in[10], (const float*)d_in[16], (const float*)d_in[22]};
    const float* cw2[3] = {(const float*)d_in[11], (const float*)d_in[17], (const float*)d_in[23]};
    const float* cb2[3] = {(const float*)d_in[12], (const float*)d_in[18], (const float*)d_in[24]};
    const float* fc1w = (const float*)d_in[25];
    const float* fc1b = (const float*)d_in[26];
    const float* clsw = (const float*)d_in[27];
    const float* clsb = (const float*)d_in[28];

    const int N = in_sizes[0] / XF;
    const int E = in_sizes[1] / 2;
    const int G = out_size / 202;
    const int Mpad = (N + 63) & ~63;
    const int NBK = (N + 255) >> BSHIFT;        // dst buckets
    const int EPB = (E + NBLK_G - 1) / NBLK_G;  // edges per count/scatter block
    const int BM = NBK * NBLK_G;                // bmat elements
    const int NB2 = (BM + 1023) / 1024;         // scan chunks for bmat

    char* p = (char*)d_ws;
    auto alloc = [&](size_t bytes) {
        char* r = p;
        p += (bytes + 255) & ~(size_t)255;
        return r;
    };
    _Float16* h16  = (_Float16*)alloc((size_t)Mpad * 128 * 2);
    _Float16* C16  = (_Float16*)alloc((size_t)Mpad * 128 * 2);
    _Float16* HH16 = (_Float16*)alloc((size_t)Mpad * 256 * 2);
    _Float16* xd16 = HH16; // alias: xd16 dead before gemm1 writes HH16
    _Float16* W16  = (_Float16*)alloc((size_t)6 * 32768 * 2);
    int* packed   = (int*)alloc((size_t)E * 4);
    int* esrc     = (int*)alloc((size_t)E * 4);
    int* indptr   = (int*)alloc((size_t)(N + 1) * 4);
    int* bmat     = (int*)alloc((size_t)BM * 4);
    int* blocksum = (int*)alloc((size_t)NB2 * 4);
    int* gcount   = (int*)alloc((size_t)G * 4);
    int* gcur     = (int*)alloc((size_t)G * 4);
    int* gindptr  = (int*)alloc((size_t)(G + 1) * 4);
    int* gnodes   = (int*)alloc((size_t)N * 4);
    float* rbuf   = (float*)alloc((size_t)6 * G * NF * 4);

    hipMemsetAsync(gcount, 0, (size_t)G * 4, stream);

    // CSR build: count -> scan -> scatter -> finalize (all data atomics in LDS)
    csr_count_kernel<<<NBLK_G, 256, 0, stream>>>(eidx, bmat, E, NBK, EPB);
    scan1x_kernel<<<NB2, 256, 0, stream>>>(bmat, blocksum, BM);
    scan2_kernel<<<1, 64, 0, stream>>>(blocksum, NB2);
    scan3x_kernel<<<(BM + 255) / 256, 256, 0, stream>>>(bmat, blocksum, BM);
    csr_scatter_kernel<<<NBLK_G, 256, 0, stream>>>(eidx, bmat, packed, E, NBK, EPB);
    csr_finalize_kernel<<<NBK, 256, 0, stream>>>(bmat, packed, indptr, esrc, E, NBK, N);

    // batch-CSR for readout
    gcnt_kernel<<<(N + 255) / 256, 256, 0, stream>>>(batch, gcount, N);
    small_scan_kernel<<<1, 256, 0, stream>>>(gcount, 1, gcur, 1, gindptr, G);
    gfill_kernel<<<(N + 255) / 256, 256, 0, stream>>>(batch, gcur, gnodes, N);

    // weights -> fp16 (padded)
    WArgs wa;
    for (int l = 0; l < 3; ++l) {
        wa.src[l] = cw1[l];     wa.dst[l] = W16 + (size_t)l * 32768;
        wa.src[3 + l] = cw2[l]; wa.dst[3 + l] = W16 + (size_t)(3 + l) * 32768;
    }
    wconv_kernel<<<dim3(128, 6), 256, 0, stream>>>(wa);

    // layer-1 input transforms
    lin10_kernel<<<((size_t)N * 64 + 255) / 256, 256, 0, stream>>>(x, c1_src_w, c1_src_b,
                                                                   c1_dst_w, c1_dst_b, h16, xd16, N);

    for (int l = 0; l < 3; ++l) {
        const _Float16* xdp = (l == 0) ? xd16 : h16;
        agg_kernel<<<(N + 1) / 2, 128, 0, stream>>>(h16, xdp, indptr, esrc, C16, N);
        mfma_gemm_kernel<4, 128, true><<<dim3(Mpad / 64, 4), 256, 0, stream>>>(
            C16, W16 + (size_t)l * 32768, cb1[l], cg[l], cbe[l], HH16, 256, N, HF);
        mfma_gemm_kernel<8, 256, false><<<dim3(Mpad / 64, 2), 256, 0, stream>>>(
            HH16, W16 + (size_t)(3 + l) * 32768, cb2[l], nullptr, nullptr, h16, 128, N, NF);
        readout2_kernel<<<G, 256, 0, stream>>>(h16, gindptr, gnodes,
                                               rbuf + (size_t)l * G * NF,
                                               rbuf + (size_t)(3 + l) * G * NF);
    }

    head_kernel<<<G, 256, 0, stream>>>(rbuf, gindptr, fc1w, fc1b, clsw, clsb, (float*)d_out, G);
    (void)ws_size;
}

// Round 6
// 1102.388 us; speedup vs baseline: 18.7310x; 1.0257x over previous
//
#include <hip/hip_runtime.h>
#include <cstdint>
#include <cstddef>

#define XF 10
#define NF 100
#define HF 200
#define BSHIFT 8
#define NBLK_G 512   // blocks for count/scatter passes
#define MAXBK 512    // max dst buckets (N <= 131072)

typedef _Float16 f16x8 __attribute__((ext_vector_type(8)));
typedef _Float16 h2 __attribute__((ext_vector_type(2)));
typedef float f32x4 __attribute__((ext_vector_type(4)));

static __device__ __forceinline__ float bn_scale(float g) {
    return g * 0.9999950000374997f; // 1/sqrt(1 + 1e-5)
}

// ---------------- CSR build: radix partition by dst, no global data atomics ----
__global__ __launch_bounds__(256) void csr_count_kernel(const int* __restrict__ eidx,
                                                        int* __restrict__ bmat,
                                                        int E, int nbk, int epb) {
    __shared__ int hist[MAXBK];
    for (int j = threadIdx.x; j < nbk; j += 256) hist[j] = 0;
    __syncthreads();
    int base = blockIdx.x * epb;
    int end = base + epb; if (end > E) end = E;
    for (int e = base + threadIdx.x; e < end; e += 256) {
        int d = eidx[E + e];
        atomicAdd(&hist[d >> BSHIFT], 1);
    }
    __syncthreads();
    for (int j = threadIdx.x; j < nbk; j += 256)
        bmat[(size_t)j * NBLK_G + blockIdx.x] = hist[j];
}

// chunked exclusive scan of bmat (in place), 1024 elems/chunk; blocksum = chunk totals
__global__ __launch_bounds__(256) void scan1x_kernel(int* __restrict__ a,
                                                     int* __restrict__ blocksum, int n) {
    __shared__ int s[256];
    int t = threadIdx.x;
    int base = blockIdx.x * 1024 + t * 4;
    int v[4]; int tot = 0;
#pragma unroll
    for (int i = 0; i < 4; ++i) {
        v[i] = (base + i < n) ? a[base + i] : 0;
        tot += v[i];
    }
    s[t] = tot;
    __syncthreads();
    for (int off = 1; off < 256; off <<= 1) {
        int add = (t >= off) ? s[t - off] : 0;
        __syncthreads();
        s[t] += add;
        __syncthreads();
    }
    int run = s[t] - tot; // exclusive within chunk
#pragma unroll
    for (int i = 0; i < 4; ++i) {
        if (base + i < n) a[base + i] = run;
        run += v[i];
    }
    if (t == 255) blocksum[blockIdx.x] = s[255];
}

// generic single-block exclusive scan for n<=1024 (strided; in-place safe)
__global__ void small_scan_kernel(const int* __restrict__ in, int in_stride,
                                  int* __restrict__ cur, int cur_stride,
                                  int* __restrict__ indptr, int n) {
    __shared__ int s[256];
    int t = threadIdx.x;
    int base = t * 4;
    int v[4]; int tot = 0;
#pragma unroll
    for (int i = 0; i < 4; ++i) {
        v[i] = (base + i < n) ? in[(base + i) * in_stride] : 0;
        tot += v[i];
    }
    s[t] = tot;
    __syncthreads();
    for (int off = 1; off < 256; off <<= 1) {
        int add = (t >= off) ? s[t - off] : 0;
        __syncthreads();
        s[t] += add;
        __syncthreads();
    }
    int run = s[t] - tot;
#pragma unroll
    for (int i = 0; i < 4; ++i) {
        if (base + i < n) {
            cur[(base + i) * cur_stride] = run;
            run += v[i];
            if (indptr) indptr[base + i + 1] = run;
        }
    }
    if (t == 0 && indptr) indptr[0] = 0;
}

// scatter packed (src | dlocal<<24); cursor = bmat chunk-scan + blocksum offset
__global__ __launch_bounds__(256) void csr_scatter_kernel(const int* __restrict__ eidx,
                                                          const int* __restrict__ bmat,
                                                          const int* __restrict__ blocksum,
                                                          int* __restrict__ packed,
                                                          int E, int nbk, int epb) {
    __shared__ int cur[MAXBK];
    for (int j = threadIdx.x; j < nbk; j += 256) {
        size_t idx = (size_t)j * NBLK_G + blockIdx.x;
        cur[j] = bmat[idx] + blocksum[idx >> 10];
    }
    __syncthreads();
    int base = blockIdx.x * epb;
    int end = base + epb; if (end > E) end = E;
    for (int e = base + threadIdx.x; e < end; e += 256) {
        int s = eidx[e];
        int d = eidx[E + e];
        int p = atomicAdd(&cur[d >> BSHIFT], 1);
        packed[p] = s | ((d & 255) << 24);
    }
}

// one block per bucket -> indptr + esrc (LDS count/scan/cursors only)
__global__ __launch_bounds__(256) void csr_finalize_kernel(const int* __restrict__ bmat,
                                                           const int* __restrict__ blocksum,
                                                           const int* __restrict__ packed,
                                                           int* __restrict__ indptr,
                                                           int* __restrict__ esrc,
                                                           int E, int nbk, int n) {
    __shared__ int cnt[256];
    __shared__ int s[256];
    __shared__ int cur[256];
    int b = blockIdx.x;
    int t = threadIdx.x;
    size_t i0 = (size_t)b * NBLK_G;
    int ebeg = bmat[i0] + blocksum[i0 >> 10];
    int eend = E;
    if (b + 1 < nbk) {
        size_t i1 = (size_t)(b + 1) * NBLK_G;
        eend = bmat[i1] + blocksum[i1 >> 10];
    }
    cnt[t] = 0;
    __syncthreads();
    for (int i = ebeg + t; i < eend; i += 256)
        atomicAdd(&cnt[((unsigned)packed[i]) >> 24], 1);
    __syncthreads();
    int tot = cnt[t];
    s[t] = tot;
    __syncthreads();
    for (int off = 1; off < 256; off <<= 1) {
        int add = (t >= off) ? s[t - off] : 0;
        __syncthreads();
        s[t] += add;
        __syncthreads();
    }
    int off_ex = s[t] - tot; // exclusive
    int node = (b << BSHIFT) + t;
    if (node < n) indptr[node] = ebeg + off_ex;
    if (b == nbk - 1 && t == 0) indptr[n] = E;
    cur[t] = ebeg + off_ex;
    __syncthreads();
    for (int i = ebeg + t; i < eend; i += 256) {
        int p = packed[i];
        int pos = atomicAdd(&cur[((unsigned)p) >> 24], 1);
        esrc[pos] = p & 0xFFFFFF;
    }
}

// batch-CSR: per-graph node lists
__global__ __launch_bounds__(256) void gcnt_kernel(const int* __restrict__ batch,
                                                   int* __restrict__ gcount, int n) {
    int i = blockIdx.x * 256 + threadIdx.x;
    if (i < n) atomicAdd(&gcount[batch[i]], 1);
}

__global__ __launch_bounds__(256) void gfill_kernel(const int* __restrict__ batch,
                                                    int* __restrict__ gcur,
                                                    int* __restrict__ gnodes, int n) {
    int i = blockIdx.x * 256 + threadIdx.x;
    if (i >= n) return;
    int g = batch[i];
    int p = atomicAdd(&gcur[g], 1);
    gnodes[p] = i;
}

// ---------------- weight conversion to fp16, K padded ----------------
struct WArgs {
    const float* src[6];
    _Float16* dst[6];
};
__global__ __launch_bounds__(256) void wconv_kernel(WArgs wa) {
    int w = blockIdx.y;
    int idx = blockIdx.x * 256 + threadIdx.x; // < 32768
    int J, K, j, k;
    if (w < 3) { J = 200; K = 100; j = idx >> 7; k = idx & 127; }
    else       { J = 100; K = 200; j = idx >> 8; k = idx & 255; }
    float v = (j < J && k < K) ? wa.src[w][j * K + k] : 0.f;
    wa.dst[w][idx] = (_Float16)v;
}

// ---------------- layer-1 input linear (10 -> 100) -> fp16, stride 128 ---------
__global__ __launch_bounds__(256) void lin10_kernel(const float* __restrict__ x,
                                                    const float* __restrict__ sw,
                                                    const float* __restrict__ sb,
                                                    const float* __restrict__ dw,
                                                    const float* __restrict__ db,
                                                    _Float16* __restrict__ h16,
                                                    _Float16* __restrict__ xd16, int n_nodes) {
    int idx = blockIdx.x * 256 + threadIdx.x;
    if (idx >= n_nodes * 64) return;
    int n = idx >> 6, f2 = idx & 63;
    float a0 = 0.f, a1 = 0.f, b0 = 0.f, b1 = 0.f;
    if (f2 < 50) {
        int f0 = 2 * f2, f1 = 2 * f2 + 1;
        float xv[XF];
#pragma unroll
        for (int k = 0; k < XF; ++k) xv[k] = x[n * XF + k];
        a0 = sb[f0]; a1 = sb[f1]; b0 = db[f0]; b1 = db[f1];
#pragma unroll
        for (int k = 0; k < XF; ++k) {
            a0 += xv[k] * sw[f0 * XF + k];
            a1 += xv[k] * sw[f1 * XF + k];
            b0 += xv[k] * dw[f0 * XF + k];
            b1 += xv[k] * dw[f1 * XF + k];
        }
    }
    ((h2*)(h16 + (size_t)n * 128))[f2] = (h2){(_Float16)a0, (_Float16)a1};
    ((h2*)(xd16 + (size_t)n * 128))[f2] = (h2){(_Float16)b0, (_Float16)b1};
}

// ---------------- softmax aggregation: 1 wave per node, online softmax --------
// groups of 4 edges, double-buffered prefetch (8 row loads in flight)
__global__ __launch_bounds__(128) void agg_kernel(const _Float16* __restrict__ h16,
                                                  const _Float16* __restrict__ xd16,
                                                  const int* __restrict__ indptr,
                                                  const int* __restrict__ esrc,
                                                  _Float16* __restrict__ c16, int n_nodes) {
    int n = blockIdx.x * 2 + (threadIdx.x >> 6);
    if (n >= n_nodes) return;
    int lane = threadIdx.x & 63;
    int beg = __builtin_amdgcn_readfirstlane(indptr[n]);
    int end = __builtin_amdgcn_readfirstlane(indptr[n + 1]);
    int deg = end - beg;
    const h2* hb = (const h2*)h16;
    float m0 = 0.f, m1 = 0.f, d0 = 0.f, d1 = 0.f, s0 = 0.f, s1 = 0.f;
    h2 va[4], vb[4];
    if (deg > 0) {
#pragma unroll
        for (int k = 0; k < 4; ++k) {
            int j = (k < deg) ? k : deg - 1;
            int sidx = esrc[beg + j];
            va[k] = hb[(size_t)sidx * 64 + lane];
        }
    }
    for (int r = 0; r < deg; r += 4) {
        if (r + 4 < deg) {
#pragma unroll
            for (int k = 0; k < 4; ++k) {
                int j = (r + 4 + k < deg) ? r + 4 + k : deg - 1;
                int sidx = esrc[beg + j];
                vb[k] = hb[(size_t)sidx * 64 + lane];
            }
        }
        int km = deg - r; if (km > 4) km = 4;
#pragma unroll
        for (int k = 0; k < 4; ++k) {
            if (k < km) {
                float v0 = (float)va[k].x, v1 = (float)va[k].y;
                float a0 = fmaxf(v0, 0.f) + 1e-7f;
                float a1 = fmaxf(v1, 0.f) + 1e-7f;
                float nm0 = fmaxf(m0, a0), nm1 = fmaxf(m1, a1);
                float sc0 = __expf(m0 - nm0), e0 = __expf(a0 - nm0);
                float sc1 = __expf(m1 - nm1), e1 = __expf(a1 - nm1);
                d0 = d0 * sc0 + e0; s0 = s0 * sc0 + e0 * a0; m0 = nm0;
                d1 = d1 * sc1 + e1; s1 = s1 * sc1 + e1 * a1; m1 = nm1;
            }
        }
#pragma unroll
        for (int k = 0; k < 4; ++k) va[k] = vb[k];
    }
    float g0 = s0 / (d0 + 1e-16f);
    float g1 = s1 / (d1 + 1e-16f);
    float o0 = 0.f, o1 = 0.f;
    if (lane < 50) {
        h2 xv = ((const h2*)(xd16 + (size_t)n * 128))[lane];
        o0 = g0 + (float)xv.x;
        o1 = g1 + (float)xv.y;
    }
    ((h2*)(c16 + (size_t)n * 128))[lane] = (h2){(_Float16)o0, (_Float16)o1};
}

// ---------------- MFMA f16 GEMM: out16 = relu(opt-BN(A @ W^T + bias)) ---------
template <int KSTEPS, int LDA, bool BN>
__global__ __launch_bounds__(256, 4) void mfma_gemm_kernel(const _Float16* __restrict__ A,
                                                           const _Float16* __restrict__ W,
                                                           const float* __restrict__ bias,
                                                           const float* __restrict__ gamma,
                                                           const float* __restrict__ beta,
                                                           _Float16* __restrict__ out16,
                                                           int ldo, int M, int J) {
    int wave = threadIdx.x >> 6;
    int lane = threadIdx.x & 63;
    int l15 = lane & 15, quad = lane >> 4;
    long m0 = (long)blockIdx.x * 64;
    int j0 = blockIdx.y * 64 + wave * 16;
    const _Float16* aptr = A + (m0 + l15) * LDA + quad * 8;
    const _Float16* wptr = W + (size_t)(j0 + l15) * LDA + quad * 8;
    f32x4 acc0 = {0.f, 0.f, 0.f, 0.f}, acc1 = acc0, acc2 = acc0, acc3 = acc0;
#pragma unroll 2
    for (int ks = 0; ks < KSTEPS; ++ks) {
        f16x8 b  = *(const f16x8*)(wptr + ks * 32);
        f16x8 a0 = *(const f16x8*)(aptr + ks * 32);
        f16x8 a1 = *(const f16x8*)(aptr + 16 * LDA + ks * 32);
        f16x8 a2 = *(const f16x8*)(aptr + 32 * LDA + ks * 32);
        f16x8 a3 = *(const f16x8*)(aptr + 48 * LDA + ks * 32);
        acc0 = __builtin_amdgcn_mfma_f32_16x16x32_f16(a0, b, acc0, 0, 0, 0);
        acc1 = __builtin_amdgcn_mfma_f32_16x16x32_f16(a1, b, acc1, 0, 0, 0);
        acc2 = __builtin_amdgcn_mfma_f32_16x16x32_f16(a2, b, acc2, 0, 0, 0);
        acc3 = __builtin_amdgcn_mfma_f32_16x16x32_f16(a3, b, acc3, 0, 0, 0);
    }
    int col = j0 + l15;
    bool cv = col < J;
    float bi = cv ? bias[col] : 0.f;
    float gm = 1.f, bt = 0.f;
    if (BN && cv) { gm = bn_scale(gamma[col]); bt = beta[col]; }
    f32x4 accs[4] = {acc0, acc1, acc2, acc3};
#pragma unroll
    for (int i = 0; i < 4; ++i) {
#pragma unroll
        for (int r = 0; r < 4; ++r) {
            long row = m0 + i * 16 + quad * 4 + r;
            float v = accs[i][r] + bi;
            if (BN) v = v * gm + bt;
            v = fmaxf(v, 0.f);
            if (!cv) v = 0.f;
            if (row < M) out16[row * ldo + col] = (_Float16)v;
        }
    }
}

// ---------------- readout: per-graph gather (no atomics) ----------------
__global__ __launch_bounds__(256) void readout2_kernel(const _Float16* __restrict__ h16,
                                                       const int* __restrict__ gindptr,
                                                       const int* __restrict__ gnodes,
                                                       float* __restrict__ sum,
                                                       float* __restrict__ mx) {
    __shared__ float ls[4][128];
    __shared__ float lm[4][128];
    int g = blockIdx.x;
    int wave = threadIdx.x >> 6;
    int lane = threadIdx.x & 63;
    int beg = gindptr[g], end = gindptr[g + 1];
    const h2* hb = (const h2*)h16;
    float s0 = 0.f, s1 = 0.f, m0 = 0.f, m1 = 0.f;
    int i = beg + wave;
    int nd = (i < end) ? gnodes[i] : 0;
    for (; i < end; i += 4) {
        int ndn = (i + 4 < end) ? gnodes[i + 4] : 0;
        h2 v = hb[(size_t)nd * 64 + lane];
        float v0 = (float)v.x, v1 = (float)v.y;
        s0 += v0; s1 += v1;
        m0 = fmaxf(m0, v0); m1 = fmaxf(m1, v1);
        nd = ndn;
    }
    ls[wave][2 * lane] = s0; ls[wave][2 * lane + 1] = s1;
    lm[wave][2 * lane] = m0; lm[wave][2 * lane + 1] = m1;
    __syncthreads();
    int f = threadIdx.x;
    if (f < NF) {
        float ss = ls[0][f] + ls[1][f] + ls[2][f] + ls[3][f];
        float mm = fmaxf(fmaxf(lm[0][f], lm[1][f]), fmaxf(lm[2][f], lm[3][f]));
        sum[(size_t)g * NF + f] = ss;
        mx[(size_t)g * NF + f] = mm;
    }
}

// ---------------- head: encode + fc1 + classifier ----------------
__global__ __launch_bounds__(256) void head_kernel(const float* __restrict__ rbuf,
                                                   const int* __restrict__ gindptr,
                                                   const float* __restrict__ fc1w,
                                                   const float* __restrict__ fc1b,
                                                   const float* __restrict__ clsw,
                                                   const float* __restrict__ clsb,
                                                   float* __restrict__ out, int G) {
    __shared__ float enc[HF];
    __shared__ float z[NF];
    int g = blockIdx.x;
    int t = threadIdx.x;
    const float* sum1 = rbuf;
    const float* sum2 = rbuf + (size_t)G * NF;
    const float* sum3 = rbuf + (size_t)2 * G * NF;
    const float* mx1 = rbuf + (size_t)3 * G * NF;
    const float* mx2 = rbuf + (size_t)4 * G * NF;
    const float* mx3 = rbuf + (size_t)5 * G * NF;
    float ic = 1.f / fmaxf((float)(gindptr[g + 1] - gindptr[g]), 1.f);
    if (t < HF) {
        float e;
        if (t < NF) {
            e = fmaxf(sum1[g * NF + t] * ic, 0.f) + fmaxf(sum2[g * NF + t] * ic, 0.f) +
                fmaxf(sum3[g * NF + t] * ic, 0.f);
        } else {
            int f = t - NF;
            e = fmaxf(mx1[g * NF + f], 0.f) + fmaxf(mx2[g * NF + f], 0.f) +
                fmaxf(mx3[g * NF + f], 0.f);
        }
        enc[t] = e;
        out[G * 2 + (size_t)g * HF + t] = e;
    }
    __syncthreads();
    if (t < NF) {
        float a = fc1b[t];
        for (int k = 0; k < HF; ++k) a += enc[k] * fc1w[t * HF + k];
        z[t] = fmaxf(a, 0.f);
    }
    __syncthreads();
    if (t < 2) {
        float a = clsb[t];
        for (int k = 0; k < NF; ++k) a += z[k] * clsw[t * NF + k];
        out[(size_t)g * 2 + t] = a;
    }
}

extern "C" void kernel_launch(void* const* d_in, const int* in_sizes, int n_in,
                              void* d_out, int out_size, void* d_ws, size_t ws_size,
                              hipStream_t stream) {
    const float* x        = (const float*)d_in[0];
    const int*   eidx     = (const int*)d_in[1];
    const int*   batch    = (const int*)d_in[2];
    const float* c1_src_w = (const float*)d_in[3];
    const float* c1_src_b = (const float*)d_in[4];
    const float* c1_dst_w = (const float*)d_in[5];
    const float* c1_dst_b = (const float*)d_in[6];
    const float* cw1[3] = {(const float*)d_in[7],  (const float*)d_in[13], (const float*)d_in[19]};
    const float* cb1[3] = {(const float*)d_in[8],  (const float*)d_in[14], (const float*)d_in[20]};
    const float* cg[3]  = {(const float*)d_in[9],  (const float*)d_in[15], (const float*)d_in[21]};
    const float* cbe[3] = {(const float*)d_in[10], (const float*)d_in[16], (const float*)d_in[22]};
    const float* cw2[3] = {(const float*)d_in[11], (const float*)d_in[17], (const float*)d_in[23]};
    const float* cb2[3] = {(const float*)d_in[12], (const float*)d_in[18], (const float*)d_in[24]};
    const float* fc1w = (const float*)d_in[25];
    const float* fc1b = (const float*)d_in[26];
    const float* clsw = (const float*)d_in[27];
    const float* clsb = (const float*)d_in[28];

    const int N = in_sizes[0] / XF;
    const int E = in_sizes[1] / 2;
    const int G = out_size / 202;
    const int Mpad = (N + 63) & ~63;
    const int NBK = (N + 255) >> BSHIFT;        // dst buckets
    const int EPB = (E + NBLK_G - 1) / NBLK_G;  // edges per count/scatter block
    const int BM = NBK * NBLK_G;                // bmat elements
    const int NB2 = (BM + 1023) / 1024;         // scan chunks for bmat

    char* p = (char*)d_ws;
    auto alloc = [&](size_t bytes) {
        char* r = p;
        p += (bytes + 255) & ~(size_t)255;
        return r;
    };
    _Float16* h16  = (_Float16*)alloc((size_t)Mpad * 128 * 2);
    _Float16* C16  = (_Float16*)alloc((size_t)Mpad * 128 * 2);
    _Float16* HH16 = (_Float16*)alloc((size_t)Mpad * 256 * 2);
    _Float16* xd16 = HH16; // alias: xd16 dead before gemm1 writes HH16
    _Float16* W16  = (_Float16*)alloc((size_t)6 * 32768 * 2);
    int* packed   = (int*)alloc((size_t)E * 4);
    int* esrc     = (int*)alloc((size_t)E * 4);
    int* indptr   = (int*)alloc((size_t)(N + 1) * 4);
    int* bmat     = (int*)alloc((size_t)BM * 4);
    int* blocksum = (int*)alloc((size_t)NB2 * 4);
    int* gcount   = (int*)alloc((size_t)G * 4);
    int* gcur     = (int*)alloc((size_t)G * 4);
    int* gindptr  = (int*)alloc((size_t)(G + 1) * 4);
    int* gnodes   = (int*)alloc((size_t)N * 4);
    float* rbuf   = (float*)alloc((size_t)6 * G * NF * 4);

    hipMemsetAsync(gcount, 0, (size_t)G * 4, stream);

    // CSR build: count -> chunk-scan -> parallel top scan -> scatter -> finalize
    csr_count_kernel<<<NBLK_G, 256, 0, stream>>>(eidx, bmat, E, NBK, EPB);
    scan1x_kernel<<<NB2, 256, 0, stream>>>(bmat, blocksum, BM);
    small_scan_kernel<<<1, 256, 0, stream>>>(blocksum, 1, blocksum, 1, nullptr, NB2);
    csr_scatter_kernel<<<NBLK_G, 256, 0, stream>>>(eidx, bmat, blocksum, packed, E, NBK, EPB);
    csr_finalize_kernel<<<NBK, 256, 0, stream>>>(bmat, blocksum, packed, indptr, esrc, E, NBK, N);

    // batch-CSR for readout
    gcnt_kernel<<<(N + 255) / 256, 256, 0, stream>>>(batch, gcount, N);
    small_scan_kernel<<<1, 256, 0, stream>>>(gcount, 1, gcur, 1, gindptr, G);
    gfill_kernel<<<(N + 255) / 256, 256, 0, stream>>>(batch, gcur, gnodes, N);

    // weights -> fp16 (padded)
    WArgs wa;
    for (int l = 0; l < 3; ++l) {
        wa.src[l] = cw1[l];     wa.dst[l] = W16 + (size_t)l * 32768;
        wa.src[3 + l] = cw2[l]; wa.dst[3 + l] = W16 + (size_t)(3 + l) * 32768;
    }
    wconv_kernel<<<dim3(128, 6), 256, 0, stream>>>(wa);

    // layer-1 input transforms
    lin10_kernel<<<((size_t)N * 64 + 255) / 256, 256, 0, stream>>>(x, c1_src_w, c1_src_b,
                                                                   c1_dst_w, c1_dst_b, h16, xd16, N);

    for (int l = 0; l < 3; ++l) {
        const _Float16* xdp = (l == 0) ? xd16 : h16;
        agg_kernel<<<(N + 1) / 2, 128, 0, stream>>>(h16, xdp, indptr, esrc, C16, N);
        mfma_gemm_kernel<4, 128, true><<<dim3(Mpad / 64, 4), 256, 0, stream>>>(
            C16, W16 + (size_t)l * 32768, cb1[l], cg[l], cbe[l], HH16, 256, N, HF);
        mfma_gemm_kernel<8, 256, false><<<dim3(Mpad / 64, 2), 256, 0, stream>>>(
            HH16, W16 + (size_t)(3 + l) * 32768, cb2[l], nullptr, nullptr, h16, 128, N, NF);
        readout2_kernel<<<G, 256, 0, stream>>>(h16, gindptr, gnodes,
                                               rbuf + (size_t)l * G * NF,
                                               rbuf + (size_t)(3 + l) * G * NF);
    }

    head_kernel<<<G, 256, 0, stream>>>(rbuf, gindptr, fc1w, fc1b, clsw, clsb, (float*)d_out, G);
    (void)ws_size;
}

// Round 8
// 927.765 us; speedup vs baseline: 22.2565x; 1.1882x over previous
//
#include <hip/hip_runtime.h>
#include <cstdint>
#include <cstddef>

#define XF 10
#define NF 100
#define HF 200
#define BSHIFT 8
#define NBLK_G 512   // blocks for count/scatter passes
#define MAXBK 512    // max dst buckets (N <= 131072)
#define RCH 4        // readout chunks per graph

typedef _Float16 f16x8 __attribute__((ext_vector_type(8)));
typedef _Float16 h2 __attribute__((ext_vector_type(2)));
typedef float f32x4 __attribute__((ext_vector_type(4)));

static __device__ __forceinline__ float bn_scale(float g) {
    return g * 0.9999950000374997f; // 1/sqrt(1 + 1e-5)
}

// ---------------- CSR build: radix partition by dst, no global data atomics ----
__global__ __launch_bounds__(256) void csr_count_kernel(const int* __restrict__ eidx,
                                                        int* __restrict__ bmat,
                                                        int E, int nbk, int epb) {
    __shared__ int hist[MAXBK];
    for (int j = threadIdx.x; j < nbk; j += 256) hist[j] = 0;
    __syncthreads();
    int base = blockIdx.x * epb;
    int end = base + epb; if (end > E) end = E;
    for (int e = base + threadIdx.x; e < end; e += 256) {
        int d = eidx[E + e];
        atomicAdd(&hist[d >> BSHIFT], 1);
    }
    __syncthreads();
    for (int j = threadIdx.x; j < nbk; j += 256)
        bmat[(size_t)j * NBLK_G + blockIdx.x] = hist[j];
}

// chunked exclusive scan of bmat (in place), 1024 elems/chunk; blocksum = chunk totals
__global__ __launch_bounds__(256) void scan1x_kernel(int* __restrict__ a,
                                                     int* __restrict__ blocksum, int n) {
    __shared__ int s[256];
    int t = threadIdx.x;
    int base = blockIdx.x * 1024 + t * 4;
    int v[4]; int tot = 0;
#pragma unroll
    for (int i = 0; i < 4; ++i) {
        v[i] = (base + i < n) ? a[base + i] : 0;
        tot += v[i];
    }
    s[t] = tot;
    __syncthreads();
    for (int off = 1; off < 256; off <<= 1) {
        int add = (t >= off) ? s[t - off] : 0;
        __syncthreads();
        s[t] += add;
        __syncthreads();
    }
    int run = s[t] - tot; // exclusive within chunk
#pragma unroll
    for (int i = 0; i < 4; ++i) {
        if (base + i < n) a[base + i] = run;
        run += v[i];
    }
    if (t == 255) blocksum[blockIdx.x] = s[255];
}

// generic single-block exclusive scan for n<=1024 (strided; in-place safe)
__global__ void small_scan_kernel(const int* __restrict__ in, int in_stride,
                                  int* __restrict__ cur, int cur_stride,
                                  int* __restrict__ indptr, int n) {
    __shared__ int s[256];
    int t = threadIdx.x;
    int base = t * 4;
    int v[4]; int tot = 0;
#pragma unroll
    for (int i = 0; i < 4; ++i) {
        v[i] = (base + i < n) ? in[(base + i) * in_stride] : 0;
        tot += v[i];
    }
    s[t] = tot;
    __syncthreads();
    for (int off = 1; off < 256; off <<= 1) {
        int add = (t >= off) ? s[t - off] : 0;
        __syncthreads();
        s[t] += add;
        __syncthreads();
    }
    int run = s[t] - tot;
#pragma unroll
    for (int i = 0; i < 4; ++i) {
        if (base + i < n) {
            cur[(base + i) * cur_stride] = run;
            run += v[i];
            if (indptr) indptr[base + i + 1] = run;
        }
    }
    if (t == 0 && indptr) indptr[0] = 0;
}

// scatter packed (src | dlocal<<24); cursor = bmat chunk-scan + blocksum offset
__global__ __launch_bounds__(256) void csr_scatter_kernel(const int* __restrict__ eidx,
                                                          const int* __restrict__ bmat,
                                                          const int* __restrict__ blocksum,
                                                          int* __restrict__ packed,
                                                          int E, int nbk, int epb) {
    __shared__ int cur[MAXBK];
    for (int j = threadIdx.x; j < nbk; j += 256) {
        size_t idx = (size_t)j * NBLK_G + blockIdx.x;
        cur[j] = bmat[idx] + blocksum[idx >> 10];
    }
    __syncthreads();
    int base = blockIdx.x * epb;
    int end = base + epb; if (end > E) end = E;
    for (int e = base + threadIdx.x; e < end; e += 256) {
        int s = eidx[e];
        int d = eidx[E + e];
        int p = atomicAdd(&cur[d >> BSHIFT], 1);
        packed[p] = s | ((d & 255) << 24);
    }
}

// one block per bucket -> indptr + esrc (LDS count/scan/cursors only)
__global__ __launch_bounds__(256) void csr_finalize_kernel(const int* __restrict__ bmat,
                                                           const int* __restrict__ blocksum,
                                                           const int* __restrict__ packed,
                                                           int* __restrict__ indptr,
                                                           int* __restrict__ esrc,
                                                           int E, int nbk, int n) {
    __shared__ int cnt[256];
    __shared__ int s[256];
    __shared__ int cur[256];
    int b = blockIdx.x;
    int t = threadIdx.x;
    size_t i0 = (size_t)b * NBLK_G;
    int ebeg = bmat[i0] + blocksum[i0 >> 10];
    int eend = E;
    if (b + 1 < nbk) {
        size_t i1 = (size_t)(b + 1) * NBLK_G;
        eend = bmat[i1] + blocksum[i1 >> 10];
    }
    cnt[t] = 0;
    __syncthreads();
    for (int i = ebeg + t; i < eend; i += 256)
        atomicAdd(&cnt[((unsigned)packed[i]) >> 24], 1);
    __syncthreads();
    int tot = cnt[t];
    s[t] = tot;
    __syncthreads();
    for (int off = 1; off < 256; off <<= 1) {
        int add = (t >= off) ? s[t - off] : 0;
        __syncthreads();
        s[t] += add;
        __syncthreads();
    }
    int off_ex = s[t] - tot; // exclusive
    int node = (b << BSHIFT) + t;
    if (node < n) indptr[node] = ebeg + off_ex;
    if (b == nbk - 1 && t == 0) indptr[n] = E;
    cur[t] = ebeg + off_ex;
    __syncthreads();
    for (int i = ebeg + t; i < eend; i += 256) {
        int p = packed[i];
        int pos = atomicAdd(&cur[((unsigned)p) >> 24], 1);
        esrc[pos] = p & 0xFFFFFF;
    }
}

// batch-CSR: per-graph node lists
__global__ __launch_bounds__(256) void gcnt_kernel(const int* __restrict__ batch,
                                                   int* __restrict__ gcount, int n) {
    int i = blockIdx.x * 256 + threadIdx.x;
    if (i < n) atomicAdd(&gcount[batch[i]], 1);
}

__global__ __launch_bounds__(256) void gfill_kernel(const int* __restrict__ batch,
                                                    int* __restrict__ gcur,
                                                    int* __restrict__ gnodes, int n) {
    int i = blockIdx.x * 256 + threadIdx.x;
    if (i >= n) return;
    int g = batch[i];
    int p = atomicAdd(&gcur[g], 1);
    gnodes[p] = i;
}

// ---------------- weight conversion to fp16, K padded ----------------
struct WArgs {
    const float* src[6];
    _Float16* dst[6];
};
__global__ __launch_bounds__(256) void wconv_kernel(WArgs wa) {
    int w = blockIdx.y;
    int idx = blockIdx.x * 256 + threadIdx.x; // < 32768
    int J, K, j, k;
    if (w < 3) { J = 200; K = 100; j = idx >> 7; k = idx & 127; }
    else       { J = 100; K = 200; j = idx >> 8; k = idx & 255; }
    float v = (j < J && k < K) ? wa.src[w][j * K + k] : 0.f;
    wa.dst[w][idx] = (_Float16)v;
}

// ---------------- layer-1 input linear (10 -> 100) -> fp16, stride 128 ---------
__global__ __launch_bounds__(256) void lin10_kernel(const float* __restrict__ x,
                                                    const float* __restrict__ sw,
                                                    const float* __restrict__ sb,
                                                    const float* __restrict__ dw,
                                                    const float* __restrict__ db,
                                                    _Float16* __restrict__ h16,
                                                    _Float16* __restrict__ xd16, int n_nodes) {
    int idx = blockIdx.x * 256 + threadIdx.x;
    if (idx >= n_nodes * 64) return;
    int n = idx >> 6, f2 = idx & 63;
    float a0 = 0.f, a1 = 0.f, b0 = 0.f, b1 = 0.f;
    if (f2 < 50) {
        int f0 = 2 * f2, f1 = 2 * f2 + 1;
        float xv[XF];
#pragma unroll
        for (int k = 0; k < XF; ++k) xv[k] = x[n * XF + k];
        a0 = sb[f0]; a1 = sb[f1]; b0 = db[f0]; b1 = db[f1];
#pragma unroll
        for (int k = 0; k < XF; ++k) {
            a0 += xv[k] * sw[f0 * XF + k];
            a1 += xv[k] * sw[f1 * XF + k];
            b0 += xv[k] * dw[f0 * XF + k];
            b1 += xv[k] * dw[f1 * XF + k];
        }
    }
    ((h2*)(h16 + (size_t)n * 128))[f2] = (h2){(_Float16)a0, (_Float16)a1};
    ((h2*)(xd16 + (size_t)n * 128))[f2] = (h2){(_Float16)b0, (_Float16)b1};
}

// ---------------- softmax aggregation: 1 wave per node ----------------
// No running max: e = exp2(a*log2e - 40) scales num & den identically (ratio
// exact); overflow bound moves to a~115 (values are O(1-10)); reference's
// 1e-16 eps on the unscaled den == 9.0949e-29 on the scaled den.
__global__ __launch_bounds__(128) void agg_kernel(const _Float16* __restrict__ h16,
                                                  const _Float16* __restrict__ xd16,
                                                  const int* __restrict__ indptr,
                                                  const int* __restrict__ esrc,
                                                  _Float16* __restrict__ c16, int n_nodes) {
    int n = blockIdx.x * 2 + (threadIdx.x >> 6);
    if (n >= n_nodes) return;
    int lane = threadIdx.x & 63;
    int beg = __builtin_amdgcn_readfirstlane(indptr[n]);
    int end = __builtin_amdgcn_readfirstlane(indptr[n + 1]);
    int deg = end - beg;
    const h2* hb = (const h2*)h16;
    float d0 = 0.f, d1 = 0.f, s0 = 0.f, s1 = 0.f;
    const float L2E = 1.44269504088896f;
    h2 va[4], vb[4];
    if (deg > 0) {
#pragma unroll
        for (int k = 0; k < 4; ++k) {
            int j = (k < deg) ? k : deg - 1;
            unsigned sidx = (unsigned)esrc[beg + j];
            va[k] = hb[(size_t)sidx * 64 + lane];
        }
    }
    for (int r = 0; r < deg; r += 4) {
        if (r + 4 < deg) {
#pragma unroll
            for (int k = 0; k < 4; ++k) {
                int j = (r + 4 + k < deg) ? r + 4 + k : deg - 1;
                unsigned sidx = (unsigned)esrc[beg + j];
                vb[k] = hb[(size_t)sidx * 64 + lane];
            }
        }
        int km = deg - r; if (km > 4) km = 4;
#pragma unroll
        for (int k = 0; k < 4; ++k) {
            if (k < km) {
                float a0 = fmaxf((float)va[k].x, 0.f) + 1e-7f;
                float a1 = fmaxf((float)va[k].y, 0.f) + 1e-7f;
                float e0 = __builtin_amdgcn_exp2f(fmaf(a0, L2E, -40.f));
                float e1 = __builtin_amdgcn_exp2f(fmaf(a1, L2E, -40.f));
                d0 += e0; s0 = fmaf(e0, a0, s0);
                d1 += e1; s1 = fmaf(e1, a1, s1);
            }
        }
#pragma unroll
        for (int k = 0; k < 4; ++k) va[k] = vb[k];
    }
    const float EPS = 9.094947e-29f; // 1e-16 * 2^-40
    float g0 = s0 / (d0 + EPS);
    float g1 = s1 / (d1 + EPS);
    float o0 = 0.f, o1 = 0.f;
    if (lane < 50) {
        h2 xv = ((const h2*)(xd16 + (size_t)n * 128))[lane];
        o0 = g0 + (float)xv.x;
        o1 = g1 + (float)xv.y;
    }
    ((h2*)(c16 + (size_t)n * 128))[lane] = (h2){(_Float16)o0, (_Float16)o1};
}

// ---------------- MFMA f16 GEMM: out16 = relu(opt-BN(A @ W^T + bias)) ---------
template <int KSTEPS, int LDA, bool BN>
__global__ __launch_bounds__(256, 4) void mfma_gemm_kernel(const _Float16* __restrict__ A,
                                                           const _Float16* __restrict__ W,
                                                           const float* __restrict__ bias,
                                                           const float* __restrict__ gamma,
                                                           const float* __restrict__ beta,
                                                           _Float16* __restrict__ out16,
                                                           int ldo, int M, int J) {
    int wave = threadIdx.x >> 6;
    int lane = threadIdx.x & 63;
    int l15 = lane & 15, quad = lane >> 4;
    long m0 = (long)blockIdx.x * 64;
    int j0 = blockIdx.y * 64 + wave * 16;
    const _Float16* aptr = A + (m0 + l15) * LDA + quad * 8;
    const _Float16* wptr = W + (size_t)(j0 + l15) * LDA + quad * 8;
    f32x4 acc0 = {0.f, 0.f, 0.f, 0.f}, acc1 = acc0, acc2 = acc0, acc3 = acc0;
#pragma unroll 2
    for (int ks = 0; ks < KSTEPS; ++ks) {
        f16x8 b  = *(const f16x8*)(wptr + ks * 32);
        f16x8 a0 = *(const f16x8*)(aptr + ks * 32);
        f16x8 a1 = *(const f16x8*)(aptr + 16 * LDA + ks * 32);
        f16x8 a2 = *(const f16x8*)(aptr + 32 * LDA + ks * 32);
        f16x8 a3 = *(const f16x8*)(aptr + 48 * LDA + ks * 32);
        acc0 = __builtin_amdgcn_mfma_f32_16x16x32_f16(a0, b, acc0, 0, 0, 0);
        acc1 = __builtin_amdgcn_mfma_f32_16x16x32_f16(a1, b, acc1, 0, 0, 0);
        acc2 = __builtin_amdgcn_mfma_f32_16x16x32_f16(a2, b, acc2, 0, 0, 0);
        acc3 = __builtin_amdgcn_mfma_f32_16x16x32_f16(a3, b, acc3, 0, 0, 0);
    }
    int col = j0 + l15;
    bool cv = col < J;
    float bi = cv ? bias[col] : 0.f;
    float gm = 1.f, bt = 0.f;
    if (BN && cv) { gm = bn_scale(gamma[col]); bt = beta[col]; }
    f32x4 accs[4] = {acc0, acc1, acc2, acc3};
#pragma unroll
    for (int i = 0; i < 4; ++i) {
#pragma unroll
        for (int r = 0; r < 4; ++r) {
            long row = m0 + i * 16 + quad * 4 + r;
            float v = accs[i][r] + bi;
            if (BN) v = v * gm + bt;
            v = fmaxf(v, 0.f);
            if (!cv) v = 0.f;
            if (row < M) out16[row * ldo + col] = (_Float16)v;
        }
    }
}

// ---------------- readout: per-graph gather, 4 chunks/graph -------------------
__global__ __launch_bounds__(256) void readout2_kernel(const _Float16* __restrict__ h16,
                                                       const int* __restrict__ gindptr,
                                                       const int* __restrict__ gnodes,
                                                       float* __restrict__ sumpart,
                                                       float* __restrict__ maxpart, int G) {
    __shared__ float ls[4][128];
    __shared__ float lm[4][128];
    int g = blockIdx.x, ch = blockIdx.y;
    int wave = threadIdx.x >> 6;
    int lane = threadIdx.x & 63;
    int beg = gindptr[g], end = gindptr[g + 1];
    const h2* hb = (const h2*)h16;
    float s0 = 0.f, s1 = 0.f, m0 = 0.f, m1 = 0.f;
    int i = beg + ch * 4 + wave;
    int nd = (i < end) ? gnodes[i] : 0;
    for (; i < end; i += 16) {
        int ndn = (i + 16 < end) ? gnodes[i + 16] : 0;
        h2 v = hb[(size_t)nd * 64 + lane];
        float v0 = (float)v.x, v1 = (float)v.y;
        s0 += v0; s1 += v1;
        m0 = fmaxf(m0, v0); m1 = fmaxf(m1, v1);
        nd = ndn;
    }
    ls[wave][2 * lane] = s0; ls[wave][2 * lane + 1] = s1;
    lm[wave][2 * lane] = m0; lm[wave][2 * lane + 1] = m1;
    __syncthreads();
    int f = threadIdx.x;
    if (f < NF) {
        float ss = ls[0][f] + ls[1][f] + ls[2][f] + ls[3][f];
        float mm = fmaxf(fmaxf(lm[0][f], lm[1][f]), fmaxf(lm[2][f], lm[3][f]));
        sumpart[((size_t)ch * G + g) * NF + f] = ss;
        maxpart[((size_t)ch * G + g) * NF + f] = mm;
    }
}

// ---------------- head: combine partials + encode + fc1 + classifier ----------
// rbuf layout: [(l*2+kind)*RCH + ch][G][NF], kind 0=sum 1=max
__global__ __launch_bounds__(256) void head_kernel(const float* __restrict__ rbuf,
                                                   const int* __restrict__ gindptr,
                                                   const float* __restrict__ fc1w,
                                                   const float* __restrict__ fc1b,
                                                   const float* __restrict__ clsw,
                                                   const float* __restrict__ clsb,
                                                   float* __restrict__ out, int G) {
    __shared__ float enc[HF];
    __shared__ float z[NF];
    int g = blockIdx.x;
    int t = threadIdx.x;
    float ic = 1.f / fmaxf((float)(gindptr[g + 1] - gindptr[g]), 1.f);
    if (t < HF) {
        float e = 0.f;
        if (t < NF) {
#pragma unroll
            for (int l = 0; l < 3; ++l) {
                float s = 0.f;
#pragma unroll
                for (int ch = 0; ch < RCH; ++ch)
                    s += rbuf[(((size_t)(l * 2) * RCH + ch) * G + g) * NF + t];
                e += fmaxf(s * ic, 0.f);
            }
        } else {
            int f = t - NF;
#pragma unroll
            for (int l = 0; l < 3; ++l) {
                float mm = 0.f;
#pragma unroll
                for (int ch = 0; ch < RCH; ++ch)
                    mm = fmaxf(mm, rbuf[(((size_t)(l * 2 + 1) * RCH + ch) * G + g) * NF + f]);
                e += fmaxf(mm, 0.f);
            }
        }
        enc[t] = e;
        out[G * 2 + (size_t)g * HF + t] = e;
    }
    __syncthreads();
    if (t < NF) {
        float a = fc1b[t];
        for (int k = 0; k < HF; ++k) a += enc[k] * fc1w[t * HF + k];
        z[t] = fmaxf(a, 0.f);
    }
    __syncthreads();
    if (t < 2) {
        float a = clsb[t];
        for (int k = 0; k < NF; ++k) a += z[k] * clsw[t * NF + k];
        out[(size_t)g * 2 + t] = a;
    }
}

extern "C" void kernel_launch(void* const* d_in, const int* in_sizes, int n_in,
                              void* d_out, int out_size, void* d_ws, size_t ws_size,
                              hipStream_t stream) {
    const float* x        = (const float*)d_in[0];
    const int*   eidx     = (const int*)d_in[1];
    const int*   batch    = (const int*)d_in[2];
    const float* c1_src_w = (const float*)d_in[3];
    const float* c1_src_b = (const float*)d_in[4];
    const float* c1_dst_w = (const float*)d_in[5];
    const float* c1_dst_b = (const float*)d_in[6];
    const float* cw1[3] = {(const float*)d_in[7],  (const float*)d_in[13], (const float*)d_in[19]};
    const float* cb1[3] = {(const float*)d_in[8],  (const float*)d_in[14], (const float*)d_in[20]};
    const float* cg[3]  = {(const float*)d_in[9],  (const float*)d_in[15], (const float*)d_in[21]};
    const float* cbe[3] = {(const float*)d_in[10], (const float*)d_in[16], (const float*)d_in[22]};
    const float* cw2[3] = {(const float*)d_in[11], (const float*)d_in[17], (const float*)d_in[23]};
    const float* cb2[3] = {(const float*)d_in[12], (const float*)d_in[18], (const float*)d_in[24]};
    const float* fc1w = (const float*)d_in[25];
    const float* fc1b = (const float*)d_in[26];
    const float* clsw = (const float*)d_in[27];
    const float* clsb = (const float*)d_in[28];

    const int N = in_sizes[0] / XF;
    const int E = in_sizes[1] / 2;
    const int G = out_size / 202;
    const int Mpad = (N + 63) & ~63;
    const int NBK = (N + 255) >> BSHIFT;        // dst buckets
    const int EPB = (E + NBLK_G - 1) / NBLK_G;  // edges per count/scatter block
    const int BM = NBK * NBLK_G;                // bmat elements
    const int NB2 = (BM + 1023) / 1024;         // scan chunks for bmat

    char* p = (char*)d_ws;
    auto alloc = [&](size_t bytes) {
        char* r = p;
        p += (bytes + 255) & ~(size_t)255;
        return r;
    };
    _Float16* h16  = (_Float16*)alloc((size_t)Mpad * 128 * 2);
    _Float16* C16  = (_Float16*)alloc((size_t)Mpad * 128 * 2);
    _Float16* HH16 = (_Float16*)alloc((size_t)Mpad * 256 * 2);
    _Float16* xd16 = HH16; // alias: xd16 dead before gemm1 writes HH16
    _Float16* W16  = (_Float16*)alloc((size_t)6 * 32768 * 2);
    int* packed   = (int*)alloc((size_t)E * 4);
    int* esrc     = (int*)alloc((size_t)E * 4);
    int* indptr   = (int*)alloc((size_t)(N + 1) * 4);
    int* bmat     = (int*)alloc((size_t)BM * 4);
    int* blocksum = (int*)alloc((size_t)NB2 * 4);
    int* gcount   = (int*)alloc((size_t)G * 4);
    int* gcur     = (int*)alloc((size_t)G * 4);
    int* gindptr  = (int*)alloc((size_t)(G + 1) * 4);
    int* gnodes   = (int*)alloc((size_t)N * 4);
    float* rbuf   = (float*)alloc((size_t)6 * RCH * G * NF * 4);

    (void)hipMemsetAsync(gcount, 0, (size_t)G * 4, stream);

    // CSR build: count -> chunk-scan -> parallel top scan -> scatter -> finalize
    csr_count_kernel<<<NBLK_G, 256, 0, stream>>>(eidx, bmat, E, NBK, EPB);
    scan1x_kernel<<<NB2, 256, 0, stream>>>(bmat, blocksum, BM);
    small_scan_kernel<<<1, 256, 0, stream>>>(blocksum, 1, blocksum, 1, nullptr, NB2);
    csr_scatter_kernel<<<NBLK_G, 256, 0, stream>>>(eidx, bmat, blocksum, packed, E, NBK, EPB);
    csr_finalize_kernel<<<NBK, 256, 0, stream>>>(bmat, blocksum, packed, indptr, esrc, E, NBK, N);

    // batch-CSR for readout
    gcnt_kernel<<<(N + 255) / 256, 256, 0, stream>>>(batch, gcount, N);
    small_scan_kernel<<<1, 256, 0, stream>>>(gcount, 1, gcur, 1, gindptr, G);
    gfill_kernel<<<(N + 255) / 256, 256, 0, stream>>>(batch, gcur, gnodes, N);

    // weights -> fp16 (padded)
    WArgs wa;
    for (int l = 0; l < 3; ++l) {
        wa.src[l] = cw1[l];     wa.dst[l] = W16 + (size_t)l * 32768;
        wa.src[3 + l] = cw2[l]; wa.dst[3 + l] = W16 + (size_t)(3 + l) * 32768;
    }
    wconv_kernel<<<dim3(128, 6), 256, 0, stream>>>(wa);

    // layer-1 input transforms
    lin10_kernel<<<((size_t)N * 64 + 255) / 256, 256, 0, stream>>>(x, c1_src_w, c1_src_b,
                                                                   c1_dst_w, c1_dst_b, h16, xd16, N);

    for (int l = 0; l < 3; ++l) {
        const _Float16* xdp = (l == 0) ? xd16 : h16;
        agg_kernel<<<(N + 1) / 2, 128, 0, stream>>>(h16, xdp, indptr, esrc, C16, N);
        mfma_gemm_kernel<4, 128, true><<<dim3(Mpad / 64, 4), 256, 0, stream>>>(
            C16, W16 + (size_t)l * 32768, cb1[l], cg[l], cbe[l], HH16, 256, N, HF);
        mfma_gemm_kernel<8, 256, false><<<dim3(Mpad / 64, 2), 256, 0, stream>>>(
            HH16, W16 + (size_t)(3 + l) * 32768, cb2[l], nullptr, nullptr, h16, 128, N, NF);
        readout2_kernel<<<dim3(G, RCH), 256, 0, stream>>>(
            h16, gindptr, gnodes,
            rbuf + (size_t)(l * 2) * RCH * G * NF,
            rbuf + (size_t)(l * 2 + 1) * RCH * G * NF, G);
    }

    head_kernel<<<G, 256, 0, stream>>>(rbuf, gindptr, fc1w, fc1b, clsw, clsb, (float*)d_out, G);
    (void)ws_size;
}

// Round 9
// 684.286 us; speedup vs baseline: 30.1757x; 1.3558x over previous
//
#include <hip/hip_runtime.h>
#include <cstdint>
#include <cstddef>

#define XF 10
#define NF 100
#define HF 200
#define BSHIFT 8
#define NBLK_G 512   // blocks for count/scatter passes
#define MAXBK 512    // max dst buckets (N <= 131072)
#define RCH 4        // readout chunks per graph

typedef _Float16 f16x8 __attribute__((ext_vector_type(8)));
typedef _Float16 h2 __attribute__((ext_vector_type(2)));
typedef float f32x4 __attribute__((ext_vector_type(4)));

static __device__ __forceinline__ float bn_scale(float g) {
    return g * 0.9999950000374997f; // 1/sqrt(1 + 1e-5)
}

// ---------------- CSR build: radix partition by dst, no global data atomics ----
__global__ __launch_bounds__(256) void csr_count_kernel(const int* __restrict__ eidx,
                                                        int* __restrict__ bmat,
                                                        int E, int nbk, int epb) {
    __shared__ int hist[MAXBK];
    for (int j = threadIdx.x; j < nbk; j += 256) hist[j] = 0;
    __syncthreads();
    int base = blockIdx.x * epb;
    int end = base + epb; if (end > E) end = E;
    for (int e = base + threadIdx.x; e < end; e += 256) {
        int d = eidx[E + e];
        atomicAdd(&hist[d >> BSHIFT], 1);
    }
    __syncthreads();
    for (int j = threadIdx.x; j < nbk; j += 256)
        bmat[(size_t)j * NBLK_G + blockIdx.x] = hist[j];
}

// chunked exclusive scan of bmat (in place), 1024 elems/chunk; blocksum = chunk totals
__global__ __launch_bounds__(256) void scan1x_kernel(int* __restrict__ a,
                                                     int* __restrict__ blocksum, int n) {
    __shared__ int s[256];
    int t = threadIdx.x;
    int base = blockIdx.x * 1024 + t * 4;
    int v[4]; int tot = 0;
#pragma unroll
    for (int i = 0; i < 4; ++i) {
        v[i] = (base + i < n) ? a[base + i] : 0;
        tot += v[i];
    }
    s[t] = tot;
    __syncthreads();
    for (int off = 1; off < 256; off <<= 1) {
        int add = (t >= off) ? s[t - off] : 0;
        __syncthreads();
        s[t] += add;
        __syncthreads();
    }
    int run = s[t] - tot; // exclusive within chunk
#pragma unroll
    for (int i = 0; i < 4; ++i) {
        if (base + i < n) a[base + i] = run;
        run += v[i];
    }
    if (t == 255) blocksum[blockIdx.x] = s[255];
}

// generic single-block exclusive scan for n<=1024 (strided; in-place safe)
__global__ void small_scan_kernel(const int* __restrict__ in, int in_stride,
                                  int* __restrict__ cur, int cur_stride,
                                  int* __restrict__ indptr, int n) {
    __shared__ int s[256];
    int t = threadIdx.x;
    int base = t * 4;
    int v[4]; int tot = 0;
#pragma unroll
    for (int i = 0; i < 4; ++i) {
        v[i] = (base + i < n) ? in[(base + i) * in_stride] : 0;
        tot += v[i];
    }
    s[t] = tot;
    __syncthreads();
    for (int off = 1; off < 256; off <<= 1) {
        int add = (t >= off) ? s[t - off] : 0;
        __syncthreads();
        s[t] += add;
        __syncthreads();
    }
    int run = s[t] - tot;
#pragma unroll
    for (int i = 0; i < 4; ++i) {
        if (base + i < n) {
            cur[(base + i) * cur_stride] = run;
            run += v[i];
            if (indptr) indptr[base + i + 1] = run;
        }
    }
    if (t == 0 && indptr) indptr[0] = 0;
}

// scatter packed (src | dlocal<<24); cursor = bmat chunk-scan + blocksum offset
__global__ __launch_bounds__(256) void csr_scatter_kernel(const int* __restrict__ eidx,
                                                          const int* __restrict__ bmat,
                                                          const int* __restrict__ blocksum,
                                                          int* __restrict__ packed,
                                                          int E, int nbk, int epb) {
    __shared__ int cur[MAXBK];
    for (int j = threadIdx.x; j < nbk; j += 256) {
        size_t idx = (size_t)j * NBLK_G + blockIdx.x;
        cur[j] = bmat[idx] + blocksum[idx >> 10];
    }
    __syncthreads();
    int base = blockIdx.x * epb;
    int end = base + epb; if (end > E) end = E;
    for (int e = base + threadIdx.x; e < end; e += 256) {
        int s = eidx[e];
        int d = eidx[E + e];
        int p = atomicAdd(&cur[d >> BSHIFT], 1);
        packed[p] = s | ((d & 255) << 24);
    }
}

// one block per bucket -> indptr + esrc (LDS count/scan/cursors only)
__global__ __launch_bounds__(256) void csr_finalize_kernel(const int* __restrict__ bmat,
                                                           const int* __restrict__ blocksum,
                                                           const int* __restrict__ packed,
                                                           int* __restrict__ indptr,
                                                           int* __restrict__ esrc,
                                                           int E, int nbk, int n) {
    __shared__ int cnt[256];
    __shared__ int s[256];
    __shared__ int cur[256];
    int b = blockIdx.x;
    int t = threadIdx.x;
    size_t i0 = (size_t)b * NBLK_G;
    int ebeg = bmat[i0] + blocksum[i0 >> 10];
    int eend = E;
    if (b + 1 < nbk) {
        size_t i1 = (size_t)(b + 1) * NBLK_G;
        eend = bmat[i1] + blocksum[i1 >> 10];
    }
    cnt[t] = 0;
    __syncthreads();
    for (int i = ebeg + t; i < eend; i += 256)
        atomicAdd(&cnt[((unsigned)packed[i]) >> 24], 1);
    __syncthreads();
    int tot = cnt[t];
    s[t] = tot;
    __syncthreads();
    for (int off = 1; off < 256; off <<= 1) {
        int add = (t >= off) ? s[t - off] : 0;
        __syncthreads();
        s[t] += add;
        __syncthreads();
    }
    int off_ex = s[t] - tot; // exclusive
    int node = (b << BSHIFT) + t;
    if (node < n) indptr[node] = ebeg + off_ex;
    if (b == nbk - 1 && t == 0) indptr[n] = E;
    cur[t] = ebeg + off_ex;
    __syncthreads();
    for (int i = ebeg + t; i < eend; i += 256) {
        int p = packed[i];
        int pos = atomicAdd(&cur[((unsigned)p) >> 24], 1);
        esrc[pos] = p & 0xFFFFFF;
    }
}

// batch-CSR: per-graph node lists
__global__ __launch_bounds__(256) void gcnt_kernel(const int* __restrict__ batch,
                                                   int* __restrict__ gcount, int n) {
    int i = blockIdx.x * 256 + threadIdx.x;
    if (i < n) atomicAdd(&gcount[batch[i]], 1);
}

__global__ __launch_bounds__(256) void gfill_kernel(const int* __restrict__ batch,
                                                    int* __restrict__ gcur,
                                                    int* __restrict__ gnodes, int n) {
    int i = blockIdx.x * 256 + threadIdx.x;
    if (i >= n) return;
    int g = batch[i];
    int p = atomicAdd(&gcur[g], 1);
    gnodes[p] = i;
}

// ---------------- weight conversion to fp16, K padded ----------------
struct WArgs {
    const float* src[6];
    _Float16* dst[6];
};
__global__ __launch_bounds__(256) void wconv_kernel(WArgs wa) {
    int w = blockIdx.y;
    int idx = blockIdx.x * 256 + threadIdx.x; // < 32768
    int J, K, j, k;
    if (w < 3) { J = 200; K = 100; j = idx >> 7; k = idx & 127; }
    else       { J = 100; K = 200; j = idx >> 8; k = idx & 255; }
    float v = (j < J && k < K) ? wa.src[w][j * K + k] : 0.f;
    wa.dst[w][idx] = (_Float16)v;
}

// ---------------- layer-1 input linear (10 -> 100) -> fp16, stride 128 ---------
__global__ __launch_bounds__(256) void lin10_kernel(const float* __restrict__ x,
                                                    const float* __restrict__ sw,
                                                    const float* __restrict__ sb,
                                                    const float* __restrict__ dw,
                                                    const float* __restrict__ db,
                                                    _Float16* __restrict__ h16,
                                                    _Float16* __restrict__ xd16, int n_nodes) {
    int idx = blockIdx.x * 256 + threadIdx.x;
    if (idx >= n_nodes * 64) return;
    int n = idx >> 6, f2 = idx & 63;
    float a0 = 0.f, a1 = 0.f, b0 = 0.f, b1 = 0.f;
    if (f2 < 50) {
        int f0 = 2 * f2, f1 = 2 * f2 + 1;
        float xv[XF];
#pragma unroll
        for (int k = 0; k < XF; ++k) xv[k] = x[n * XF + k];
        a0 = sb[f0]; a1 = sb[f1]; b0 = db[f0]; b1 = db[f1];
#pragma unroll
        for (int k = 0; k < XF; ++k) {
            a0 += xv[k] * sw[f0 * XF + k];
            a1 += xv[k] * sw[f1 * XF + k];
            b0 += xv[k] * dw[f0 * XF + k];
            b1 += xv[k] * dw[f1 * XF + k];
        }
    }
    ((h2*)(h16 + (size_t)n * 128))[f2] = (h2){(_Float16)a0, (_Float16)a1};
    ((h2*)(xd16 + (size_t)n * 128))[f2] = (h2){(_Float16)b0, (_Float16)b1};
}

// ---------------- softmax aggregation: 1 wave per node ----------------
__global__ __launch_bounds__(128) void agg_kernel(const _Float16* __restrict__ h16,
                                                  const _Float16* __restrict__ xd16,
                                                  const int* __restrict__ indptr,
                                                  const int* __restrict__ esrc,
                                                  _Float16* __restrict__ c16, int n_nodes) {
    int n = blockIdx.x * 2 + (threadIdx.x >> 6);
    if (n >= n_nodes) return;
    int lane = threadIdx.x & 63;
    int beg = __builtin_amdgcn_readfirstlane(indptr[n]);
    int end = __builtin_amdgcn_readfirstlane(indptr[n + 1]);
    int deg = end - beg;
    const h2* hb = (const h2*)h16;
    float d0 = 0.f, d1 = 0.f, s0 = 0.f, s1 = 0.f;
    const float L2E = 1.44269504088896f;
    h2 va[4], vb[4];
    if (deg > 0) {
#pragma unroll
        for (int k = 0; k < 4; ++k) {
            int j = (k < deg) ? k : deg - 1;
            unsigned sidx = (unsigned)esrc[beg + j];
            va[k] = hb[(size_t)sidx * 64 + lane];
        }
    }
    for (int r = 0; r < deg; r += 4) {
        if (r + 4 < deg) {
#pragma unroll
            for (int k = 0; k < 4; ++k) {
                int j = (r + 4 + k < deg) ? r + 4 + k : deg - 1;
                unsigned sidx = (unsigned)esrc[beg + j];
                vb[k] = hb[(size_t)sidx * 64 + lane];
            }
        }
        int km = deg - r; if (km > 4) km = 4;
#pragma unroll
        for (int k = 0; k < 4; ++k) {
            if (k < km) {
                float a0 = fmaxf((float)va[k].x, 0.f) + 1e-7f;
                float a1 = fmaxf((float)va[k].y, 0.f) + 1e-7f;
                float e0 = __builtin_amdgcn_exp2f(fmaf(a0, L2E, -40.f));
                float e1 = __builtin_amdgcn_exp2f(fmaf(a1, L2E, -40.f));
                d0 += e0; s0 = fmaf(e0, a0, s0);
                d1 += e1; s1 = fmaf(e1, a1, s1);
            }
        }
#pragma unroll
        for (int k = 0; k < 4; ++k) va[k] = vb[k];
    }
    const float EPS = 9.094947e-29f; // 1e-16 * 2^-40
    float g0 = s0 / (d0 + EPS);
    float g1 = s1 / (d1 + EPS);
    float o0 = 0.f, o1 = 0.f;
    if (lane < 50) {
        h2 xv = ((const h2*)(xd16 + (size_t)n * 128))[lane];
        o0 = g0 + (float)xv.x;
        o1 = g1 + (float)xv.y;
    }
    ((h2*)(c16 + (size_t)n * 128))[lane] = (h2){(_Float16)o0, (_Float16)o1};
}

// ---------------- fused MLP: h = relu(BN(C@W1^T+b1)) @ W2^T + b2, relu -------
// One block = 64 node-rows. Stage 1: each wave computes 64 of the 256 HH cols
// (no redundant A reads), BN+ReLU, park in LDS (stride 264 halfs = 528 B =
// 33*16B -> b128 reads 2-way bank-aliased = free). Stage 2: LDS tile @ W2.
// HH never touches HBM (was 153 MB/layer of traffic).
__global__ __launch_bounds__(256, 3) void mlp_fused_kernel(const _Float16* __restrict__ A,
                                                           const _Float16* __restrict__ W1,
                                                           const float* __restrict__ b1v,
                                                           const float* __restrict__ g1v,
                                                           const float* __restrict__ be1v,
                                                           const _Float16* __restrict__ W2,
                                                           const float* __restrict__ b2v,
                                                           _Float16* __restrict__ out16,
                                                           int M) {
    __shared__ _Float16 hh[64][264];
    int wave = threadIdx.x >> 6;
    int lane = threadIdx.x & 63;
    int l15 = lane & 15, quad = lane >> 4;
    long m0 = (long)blockIdx.x * 64;

    // stage 1: HH[64 x 256], wave covers cols [wave*64, wave*64+64)
    const _Float16* aptr = A + (m0 + l15) * 128 + quad * 8;
    const _Float16* w1p  = W1 + (size_t)(wave * 64 + l15) * 128 + quad * 8;
    f32x4 acc[4][4] = {};
#pragma unroll 2
    for (int ks = 0; ks < 4; ++ks) {
        f16x8 bfr[4], afr[4];
#pragma unroll
        for (int ct = 0; ct < 4; ++ct) bfr[ct] = *(const f16x8*)(w1p + (size_t)ct * 16 * 128 + ks * 32);
#pragma unroll
        for (int i = 0; i < 4; ++i) afr[i] = *(const f16x8*)(aptr + (size_t)i * 16 * 128 + ks * 32);
#pragma unroll
        for (int i = 0; i < 4; ++i)
#pragma unroll
            for (int ct = 0; ct < 4; ++ct)
                acc[i][ct] = __builtin_amdgcn_mfma_f32_16x16x32_f16(afr[i], bfr[ct], acc[i][ct], 0, 0, 0);
    }
#pragma unroll
    for (int ct = 0; ct < 4; ++ct) {
        int col = wave * 64 + ct * 16 + l15;
        bool cv = col < HF;
        float bi = cv ? b1v[col] : 0.f;
        float gm = cv ? bn_scale(g1v[col]) : 0.f;
        float bt = cv ? be1v[col] : 0.f;
#pragma unroll
        for (int i = 0; i < 4; ++i)
#pragma unroll
            for (int r = 0; r < 4; ++r) {
                float v = fmaxf((acc[i][ct][r] + bi) * gm + bt, 0.f);
                hh[i * 16 + quad * 4 + r][col] = (_Float16)v;
            }
    }
    __syncthreads();

    // stage 2: out[64 x 128], wave covers cols [wave*32, wave*32+32)
    const _Float16* w2p = W2 + (size_t)(wave * 32 + l15) * 256 + quad * 8;
    f32x4 o[4][2] = {};
#pragma unroll 2
    for (int ks = 0; ks < 8; ++ks) {
        f16x8 bfr[2], afr[4];
#pragma unroll
        for (int ct = 0; ct < 2; ++ct) bfr[ct] = *(const f16x8*)(w2p + (size_t)ct * 16 * 256 + ks * 32);
#pragma unroll
        for (int i = 0; i < 4; ++i) afr[i] = *(const f16x8*)(&hh[i * 16 + l15][quad * 8 + ks * 32]);
#pragma unroll
        for (int i = 0; i < 4; ++i)
#pragma unroll
            for (int ct = 0; ct < 2; ++ct)
                o[i][ct] = __builtin_amdgcn_mfma_f32_16x16x32_f16(afr[i], bfr[ct], o[i][ct], 0, 0, 0);
    }
#pragma unroll
    for (int ct = 0; ct < 2; ++ct) {
        int col = wave * 32 + ct * 16 + l15;
        bool cv = col < NF;
        float bi = cv ? b2v[col] : 0.f;
#pragma unroll
        for (int i = 0; i < 4; ++i)
#pragma unroll
            for (int r = 0; r < 4; ++r) {
                long row = m0 + i * 16 + quad * 4 + r;
                float v = fmaxf(o[i][ct][r] + bi, 0.f);
                if (!cv) v = 0.f;
                if (row < M) out16[row * 128 + col] = (_Float16)v;
            }
    }
}

// ---------------- readout: per-graph gather, 4 chunks/graph -------------------
__global__ __launch_bounds__(256) void readout2_kernel(const _Float16* __restrict__ h16,
                                                       const int* __restrict__ gindptr,
                                                       const int* __restrict__ gnodes,
                                                       float* __restrict__ sumpart,
                                                       float* __restrict__ maxpart, int G) {
    __shared__ float ls[4][128];
    __shared__ float lm[4][128];
    int g = blockIdx.x, ch = blockIdx.y;
    int wave = threadIdx.x >> 6;
    int lane = threadIdx.x & 63;
    int beg = gindptr[g], end = gindptr[g + 1];
    const h2* hb = (const h2*)h16;
    float s0 = 0.f, s1 = 0.f, m0 = 0.f, m1 = 0.f;
    int i = beg + ch * 4 + wave;
    int nd = (i < end) ? gnodes[i] : 0;
    for (; i < end; i += 16) {
        int ndn = (i + 16 < end) ? gnodes[i + 16] : 0;
        h2 v = hb[(size_t)nd * 64 + lane];
        float v0 = (float)v.x, v1 = (float)v.y;
        s0 += v0; s1 += v1;
        m0 = fmaxf(m0, v0); m1 = fmaxf(m1, v1);
        nd = ndn;
    }
    ls[wave][2 * lane] = s0; ls[wave][2 * lane + 1] = s1;
    lm[wave][2 * lane] = m0; lm[wave][2 * lane + 1] = m1;
    __syncthreads();
    int f = threadIdx.x;
    if (f < NF) {
        float ss = ls[0][f] + ls[1][f] + ls[2][f] + ls[3][f];
        float mm = fmaxf(fmaxf(lm[0][f], lm[1][f]), fmaxf(lm[2][f], lm[3][f]));
        sumpart[((size_t)ch * G + g) * NF + f] = ss;
        maxpart[((size_t)ch * G + g) * NF + f] = mm;
    }
}

// ---------------- head: combine partials + encode + fc1 + classifier ----------
__global__ __launch_bounds__(256) void head_kernel(const float* __restrict__ rbuf,
                                                   const int* __restrict__ gindptr,
                                                   const float* __restrict__ fc1w,
                                                   const float* __restrict__ fc1b,
                                                   const float* __restrict__ clsw,
                                                   const float* __restrict__ clsb,
                                                   float* __restrict__ out, int G) {
    __shared__ float enc[HF];
    __shared__ float z[NF];
    int g = blockIdx.x;
    int t = threadIdx.x;
    float ic = 1.f / fmaxf((float)(gindptr[g + 1] - gindptr[g]), 1.f);
    if (t < HF) {
        float e = 0.f;
        if (t < NF) {
#pragma unroll
            for (int l = 0; l < 3; ++l) {
                float s = 0.f;
#pragma unroll
                for (int ch = 0; ch < RCH; ++ch)
                    s += rbuf[(((size_t)(l * 2) * RCH + ch) * G + g) * NF + t];
                e += fmaxf(s * ic, 0.f);
            }
        } else {
            int f = t - NF;
#pragma unroll
            for (int l = 0; l < 3; ++l) {
                float mm = 0.f;
#pragma unroll
                for (int ch = 0; ch < RCH; ++ch)
                    mm = fmaxf(mm, rbuf[(((size_t)(l * 2 + 1) * RCH + ch) * G + g) * NF + f]);
                e += fmaxf(mm, 0.f);
            }
        }
        enc[t] = e;
        out[G * 2 + (size_t)g * HF + t] = e;
    }
    __syncthreads();
    if (t < NF) {
        float a = fc1b[t];
        for (int k = 0; k < HF; ++k) a += enc[k] * fc1w[t * HF + k];
        z[t] = fmaxf(a, 0.f);
    }
    __syncthreads();
    if (t < 2) {
        float a = clsb[t];
        for (int k = 0; k < NF; ++k) a += z[k] * clsw[t * NF + k];
        out[(size_t)g * 2 + t] = a;
    }
}

extern "C" void kernel_launch(void* const* d_in, const int* in_sizes, int n_in,
                              void* d_out, int out_size, void* d_ws, size_t ws_size,
                              hipStream_t stream) {
    const float* x        = (const float*)d_in[0];
    const int*   eidx     = (const int*)d_in[1];
    const int*   batch    = (const int*)d_in[2];
    const float* c1_src_w = (const float*)d_in[3];
    const float* c1_src_b = (const float*)d_in[4];
    const float* c1_dst_w = (const float*)d_in[5];
    const float* c1_dst_b = (const float*)d_in[6];
    const float* cw1[3] = {(const float*)d_in[7],  (const float*)d_in[13], (const float*)d_in[19]};
    const float* cb1[3] = {(const float*)d_in[8],  (const float*)d_in[14], (const float*)d_in[20]};
    const float* cg[3]  = {(const float*)d_in[9],  (const float*)d_in[15], (const float*)d_in[21]};
    const float* cbe[3] = {(const float*)d_in[10], (const float*)d_in[16], (const float*)d_in[22]};
    const float* cw2[3] = {(const float*)d_in[11], (const float*)d_in[17], (const float*)d_in[23]};
    const float* cb2[3] = {(const float*)d_in[12], (const float*)d_in[18], (const float*)d_in[24]};
    const float* fc1w = (const float*)d_in[25];
    const float* fc1b = (const float*)d_in[26];
    const float* clsw = (const float*)d_in[27];
    const float* clsb = (const float*)d_in[28];

    const int N = in_sizes[0] / XF;
    const int E = in_sizes[1] / 2;
    const int G = out_size / 202;
    const int Mpad = (N + 63) & ~63;
    const int NBK = (N + 255) >> BSHIFT;        // dst buckets
    const int EPB = (E + NBLK_G - 1) / NBLK_G;  // edges per count/scatter block
    const int BM = NBK * NBLK_G;                // bmat elements
    const int NB2 = (BM + 1023) / 1024;         // scan chunks for bmat

    char* p = (char*)d_ws;
    auto alloc = [&](size_t bytes) {
        char* r = p;
        p += (bytes + 255) & ~(size_t)255;
        return r;
    };
    _Float16* h16  = (_Float16*)alloc((size_t)Mpad * 128 * 2);
    _Float16* C16  = (_Float16*)alloc((size_t)Mpad * 128 * 2);
    _Float16* xd16 = (_Float16*)alloc((size_t)Mpad * 128 * 2);
    _Float16* W16  = (_Float16*)alloc((size_t)6 * 32768 * 2);
    int* packed   = (int*)alloc((size_t)E * 4);
    int* esrc     = (int*)alloc((size_t)E * 4);
    int* indptr   = (int*)alloc((size_t)(N + 1) * 4);
    int* bmat     = (int*)alloc((size_t)BM * 4);
    int* blocksum = (int*)alloc((size_t)NB2 * 4);
    int* gcount   = (int*)alloc((size_t)G * 4);
    int* gcur     = (int*)alloc((size_t)G * 4);
    int* gindptr  = (int*)alloc((size_t)(G + 1) * 4);
    int* gnodes   = (int*)alloc((size_t)N * 4);
    float* rbuf   = (float*)alloc((size_t)6 * RCH * G * NF * 4);

    (void)hipMemsetAsync(gcount, 0, (size_t)G * 4, stream);

    // CSR build: count -> chunk-scan -> parallel top scan -> scatter -> finalize
    csr_count_kernel<<<NBLK_G, 256, 0, stream>>>(eidx, bmat, E, NBK, EPB);
    scan1x_kernel<<<NB2, 256, 0, stream>>>(bmat, blocksum, BM);
    small_scan_kernel<<<1, 256, 0, stream>>>(blocksum, 1, blocksum, 1, nullptr, NB2);
    csr_scatter_kernel<<<NBLK_G, 256, 0, stream>>>(eidx, bmat, blocksum, packed, E, NBK, EPB);
    csr_finalize_kernel<<<NBK, 256, 0, stream>>>(bmat, blocksum, packed, indptr, esrc, E, NBK, N);

    // batch-CSR for readout
    gcnt_kernel<<<(N + 255) / 256, 256, 0, stream>>>(batch, gcount, N);
    small_scan_kernel<<<1, 256, 0, stream>>>(gcount, 1, gcur, 1, gindptr, G);
    gfill_kernel<<<(N + 255) / 256, 256, 0, stream>>>(batch, gcur, gnodes, N);

    // weights -> fp16 (padded)
    WArgs wa;
    for (int l = 0; l < 3; ++l) {
        wa.src[l] = cw1[l];     wa.dst[l] = W16 + (size_t)l * 32768;
        wa.src[3 + l] = cw2[l]; wa.dst[3 + l] = W16 + (size_t)(3 + l) * 32768;
    }
    wconv_kernel<<<dim3(128, 6), 256, 0, stream>>>(wa);

    // layer-1 input transforms
    lin10_kernel<<<((size_t)N * 64 + 255) / 256, 256, 0, stream>>>(x, c1_src_w, c1_src_b,
                                                                   c1_dst_w, c1_dst_b, h16, xd16, N);

    for (int l = 0; l < 3; ++l) {
        const _Float16* xdp = (l == 0) ? xd16 : h16;
        agg_kernel<<<(N + 1) / 2, 128, 0, stream>>>(h16, xdp, indptr, esrc, C16, N);
        mlp_fused_kernel<<<Mpad / 64, 256, 0, stream>>>(
            C16, W16 + (size_t)l * 32768, cb1[l], cg[l], cbe[l],
            W16 + (size_t)(3 + l) * 32768, cb2[l], h16, N);
        readout2_kernel<<<dim3(G, RCH), 256, 0, stream>>>(
            h16, gindptr, gnodes,
            rbuf + (size_t)(l * 2) * RCH * G * NF,
            rbuf + (size_t)(l * 2 + 1) * RCH * G * NF, G);
    }

    head_kernel<<<G, 256, 0, stream>>>(rbuf, gindptr, fc1w, fc1b, clsw, clsb, (float*)d_out, G);
    (void)ws_size;
}